// Round 11
// baseline (252.271 us; speedup 1.0000x reference)
//
#include <hip/hip_runtime.h>
#include <hip/hip_bf16.h>

#define N_NODES 20000
#define N_EDGES 32768
#define DIM 128
#define N_REL 474
#define N_BASIS 64
#define TILE_E 64
#define MAXCH (N_EDGES / TILE_E + N_REL)   // 986 upper bound on chunk count
#define WSTRIDE 260                         // LDS row stride (shorts) for wmix staging

typedef __bf16 bf16x8 __attribute__((ext_vector_type(8)));
typedef float f32x4 __attribute__((ext_vector_type(4)));

// ---------- helpers ----------
__device__ __forceinline__ unsigned short f2b(float f) {   // RNE fp32 -> bf16 bits
    unsigned u = __float_as_uint(f);
    unsigned r = (u + 0x7FFFu + ((u >> 16) & 1u)) >> 16;
    return (unsigned short)r;
}
__device__ __forceinline__ float b2f(unsigned short s) {
    return __uint_as_float(((unsigned)s) << 16);
}
__device__ __forceinline__ __bf16 u2b(unsigned short u) {
    union { unsigned short u; __bf16 b; } c; c.u = u; return c.b;
}

// ---------- prep: gather xb = bf16(emb[entity]) + zero acc/denom ----------
__global__ __launch_bounds__(256) void prep_kernel(const float4* __restrict__ emb,
                                                   const int* __restrict__ entity,
                                                   ushort4* __restrict__ xb4,
                                                   float4* __restrict__ zreg, int zcount4) {
    int gtid = blockIdx.x * 256 + threadIdx.x;
    int gsz = gridDim.x * 256;
    int total4 = N_NODES * DIM / 4;
    for (int i = gtid; i < total4; i += gsz) {
        int n = i >> 5, rem = i & 31;
        float4 v = emb[(size_t)entity[n] * 32 + rem];
        ushort4 s;
        s.x = f2b(v.x); s.y = f2b(v.y); s.z = f2b(v.z); s.w = f2b(v.w);
        xb4[i] = s;
    }
    float4 z = make_float4(0.f, 0.f, 0.f, 0.f);
    for (int i = gtid; i < zcount4; i += gsz) zreg[i] = z;
}

// ---------- plan: single block — count (LDS hist) + scan + chunks + scatter ----------
__global__ __launch_bounds__(512) void plan_kernel(const int* __restrict__ etype,
                                                   int* __restrict__ offs,
                                                   int* __restrict__ eids,
                                                   int* __restrict__ chunk_r,
                                                   int* __restrict__ chunk_o,
                                                   int* __restrict__ nchunks_g) {
    __shared__ int hist[512];
    __shared__ int cur[N_REL];
    __shared__ int lnc;
    int t = threadIdx.x;
    hist[t] = 0;
    if (t == 0) lnc = 0;
    __syncthreads();
    for (int e = t; e < N_EDGES; e += 512) atomicAdd(&hist[etype[e]], 1);
    __syncthreads();
    int v = hist[t];
    // inclusive Hillis-Steele scan over 512 (same pattern as R10 scanr, proven)
    for (int d = 1; d < 512; d <<= 1) {
        int add = (t >= d) ? hist[t - d] : 0;
        __syncthreads();
        hist[t] += add;
        __syncthreads();
    }
    int excl = hist[t] - v;
    if (t < N_REL) { offs[t] = excl; cur[t] = excl; }
    if (t == 0) offs[N_REL] = N_EDGES;
    if (t < N_REL && v > 0) {
        int nc = (v + TILE_E - 1) / TILE_E;
        int cb = atomicAdd(&lnc, nc);
        for (int c = 0; c < nc; c++) { chunk_r[cb + c] = t; chunk_o[cb + c] = excl + c * TILE_E; }
    }
    __syncthreads();
    if (t == 0) *nchunks_g = lnc;
    // scatter edges into relation-CSR via LDS cursors
    for (int e = t; e < N_EDGES; e += 512) {
        int p = atomicAdd(&cur[etype[e]], 1);
        eids[p] = e;
    }
}

// ---------- fused logit + exp + denom (no max-shift; |logit| <~ 3 here, fp32-safe) ----------
__global__ __launch_bounds__(256) void logitexp_kernel(const unsigned short* __restrict__ xb,
                                                       const float* __restrict__ w,
                                                       const int* __restrict__ src,
                                                       const int* __restrict__ dst,
                                                       const int* __restrict__ et,
                                                       float* __restrict__ alpha,
                                                       float* __restrict__ den, int E) {
    int wid = (blockIdx.x * 256 + threadIdx.x) >> 6;
    int lane = threadIdx.x & 63;
    if (wid >= E) return;
    int s = src[wid], d = dst[wid], r = et[wid];
    unsigned ax = ((const unsigned*)(xb + (size_t)s * DIM))[lane];
    unsigned bx = ((const unsigned*)(xb + (size_t)d * DIM))[lane];
    float2 wv = ((const float2*)(w + (size_t)r * DIM))[lane];
    float v = b2f((unsigned short)(ax & 0xFFFF)) * wv.x * b2f((unsigned short)(bx & 0xFFFF))
            + b2f((unsigned short)(ax >> 16)) * wv.y * b2f((unsigned short)(bx >> 16));
    for (int off = 32; off > 0; off >>= 1) v += __shfl_xor(v, off, 64);
    if (lane == 0) {
        float a = expf(v);
        alpha[wid] = a;
        atomicAdd(&den[d], a);
    }
}

// ---------- W1+W2 = att @ basis via MFMA, both layers in one dispatch ----------
// grid (64 io-chunks, 16): blockIdx.y < 8 -> layer 1, else layer 2.
__global__ __launch_bounds__(256) void wmix_kernel(const float* __restrict__ att1,
                                                   const float* __restrict__ basis1,
                                                   unsigned short* __restrict__ W1,
                                                   const float* __restrict__ att2,
                                                   const float* __restrict__ basis2,
                                                   unsigned short* __restrict__ W2, int R) {
    const float* att   = (blockIdx.y < 8) ? att1 : att2;
    const float* basis = (blockIdx.y < 8) ? basis1 : basis2;
    unsigned short* W  = (blockIdx.y < 8) ? W1 : W2;
    int io0 = blockIdx.x * 256;
    int r0 = (blockIdx.y & 7) * 64;
    __shared__ unsigned short bt[64 * WSTRIDE];
    int t = threadIdx.x;
#pragma unroll
    for (int p = 0; p < 16; p++) {
        int c = t + 256 * p;
        int k = c >> 6, of = c & 63;
        float4 v = *(const float4*)(basis + (size_t)k * (DIM * DIM) + io0 + of * 4);
        ushort4 s;
        s.x = f2b(v.x); s.y = f2b(v.y); s.z = f2b(v.z); s.w = f2b(v.w);
        *(ushort4*)&bt[k * WSTRIDE + of * 4] = s;
    }
    __syncthreads();

    int w = t >> 6, l = t & 63, n = l & 15, q = l >> 4;
    f32x4 acc[4][4] = {};                       // [rt][c]
#pragma unroll
    for (int kb = 0; kb < 2; kb++) {
        int kbase = kb * 32 + q * 8;
        bf16x8 a[4];
#pragma unroll
        for (int rt = 0; rt < 4; rt++) {
            int rm = min(r0 + rt * 16 + n, R - 1);
            const float* ap = att + (size_t)rm * N_BASIS + kbase;
#pragma unroll
            for (int j = 0; j < 8; j++) a[rt][j] = u2b(f2b(ap[j]));
        }
#pragma unroll
        for (int c = 0; c < 4; c++) {
            int ob = w * 64 + c * 16 + n;
            bf16x8 b;
#pragma unroll
            for (int j = 0; j < 8; j++) b[j] = u2b(bt[(kbase + j) * WSTRIDE + ob]);
#pragma unroll
            for (int rt = 0; rt < 4; rt++)
                acc[rt][c] = __builtin_amdgcn_mfma_f32_16x16x32_bf16(a[rt], b, acc[rt][c], 0, 0, 0);
        }
    }
#pragma unroll
    for (int rt = 0; rt < 4; rt++) {
#pragma unroll
        for (int c = 0; c < 4; c++) {
            int col = io0 + w * 64 + c * 16 + n;
#pragma unroll
            for (int rg = 0; rg < 4; rg++) {
                int r = r0 + rt * 16 + q * 4 + rg;
                if (r < R) W[(size_t)r * (DIM * DIM) + col] = f2b(acc[rt][c][rg]);
            }
        }
    }
}

// ---------- msg: per 64-edge chunk, (64x128)@(128x128) MFMA + alpha-scaled atomicAdd (R10-proven) ----------
__global__ __launch_bounds__(256) void msg_kernel(const unsigned short* __restrict__ xb,
                                                  const unsigned short* __restrict__ W,
                                                  const int* __restrict__ chunk_r,
                                                  const int* __restrict__ chunk_off,
                                                  const int* __restrict__ nchunks,
                                                  const int* __restrict__ eids,
                                                  const int* __restrict__ offs,
                                                  const int* __restrict__ src,
                                                  const int* __restrict__ dst,
                                                  const float* __restrict__ ae,
                                                  const float* __restrict__ denom,
                                                  float* __restrict__ outacc) {
    if ((int)blockIdx.x >= *nchunks) return;
    int r = chunk_r[blockIdx.x];
    int base = chunk_off[blockIdx.x];
    int nE = min(TILE_E, offs[r + 1] - base);
    const unsigned short* Wr = W + (size_t)r * (DIM * DIM);

    __shared__ unsigned short wt[128 * 136];   // [k][o] pad
    __shared__ unsigned short xjf[8192];       // A-frag order, 64 edges
    __shared__ float scf[TILE_E];
    __shared__ int sdd[TILE_E];

    int t = threadIdx.x;
    if (t < TILE_E) {
        if (t < nE) {
            int e = eids[base + t];
            int d_ = dst[e];
            sdd[t] = d_;
            scf[t] = ae[e] / denom[d_];
        } else { sdd[t] = 0; scf[t] = 0.f; }
    }
    // stage A: slot c = (rt*4+kb)*64 + q*16 + m
#pragma unroll
    for (int p = 0; p < 4; p++) {
        int c = t + 256 * p;
        int g = c >> 6;
        int rt = g >> 2, kb = g & 3;
        int q = (c >> 4) & 3, m = c & 15;
        int e = rt * 16 + m;
        int oct = kb * 4 + q;
        int4 v = make_int4(0, 0, 0, 0);
        if (e < nE)
            v = *(const int4*)(xb + (size_t)src[eids[base + e]] * DIM + oct * 8);
        *(int4*)&xjf[c * 8] = v;
    }
    // stage W tile
#pragma unroll
    for (int p = 0; p < 8; p++) {
        int c = t + 256 * p;
        int k = c >> 4, oct = c & 15;
        int4 v = *(const int4*)(Wr + k * DIM + oct * 8);
        *(int4*)&wt[k * 136 + oct * 8] = v;
    }
    __syncthreads();

    int w = t >> 6, l = t & 63, n = l & 15, q = l >> 4;
    f32x4 acc[2][4] = {};                       // [ct-local][rt]
#pragma unroll
    for (int kb = 0; kb < 4; kb++) {
        bf16x8 a[4];
#pragma unroll
        for (int rt = 0; rt < 4; rt++) a[rt] = *(const bf16x8*)&xjf[((rt * 4 + kb) * 64 + l) * 8];
        int kbase = kb * 32 + q * 8;
#pragma unroll
        for (int c = 0; c < 2; c++) {
            int ob = (w * 2 + c) * 16 + n;
            bf16x8 b;
#pragma unroll
            for (int j = 0; j < 8; j++) b[j] = u2b(wt[(kbase + j) * 136 + ob]);
#pragma unroll
            for (int rt = 0; rt < 4; rt++)
                acc[c][rt] = __builtin_amdgcn_mfma_f32_16x16x32_bf16(a[rt], b, acc[c][rt], 0, 0, 0);
        }
    }
#pragma unroll
    for (int c = 0; c < 2; c++) {
        int col = (w * 2 + c) * 16 + n;
#pragma unroll
        for (int rt = 0; rt < 4; rt++) {
#pragma unroll
            for (int rg = 0; rg < 4; rg++) {
                int e = rt * 16 + q * 4 + rg;
                if (e < nE)
                    atomicAdd(&outacc[(size_t)sdd[e] * DIM + col], scf[e] * acc[c][rt][rg]);
            }
        }
    }
}

// ---------- root: out = acc + x @ root + bias via MFMA; mode 1 = relu+bf16, 0 = fp32 (R10-proven) ----------
__global__ __launch_bounds__(256) void root_kernel(const unsigned short* __restrict__ xb,
                                                   const float* __restrict__ rootM,
                                                   const float* __restrict__ bias,
                                                   const float* __restrict__ accbuf,
                                                   unsigned short* __restrict__ outb,
                                                   float* __restrict__ outf,
                                                   int mode, int N) {
    int n0 = blockIdx.x * 64;
    __shared__ unsigned short wt[128 * 136];
    __shared__ unsigned short xrf[8192];
    int t = threadIdx.x;
#pragma unroll
    for (int p = 0; p < 4; p++) {
        int c = t + 256 * p;
        int g = c >> 6;
        int rt = g >> 2, kb = g & 3;
        int q = (c >> 4) & 3, m = c & 15;
        int row = n0 + rt * 16 + m;
        int oct = kb * 4 + q;
        int4 v = make_int4(0, 0, 0, 0);
        if (row < N) v = *(const int4*)(xb + (size_t)row * DIM + oct * 8);
        *(int4*)&xrf[c * 8] = v;
    }
#pragma unroll
    for (int p = 0; p < 16; p++) {
        int c = t + 256 * p;
        int k = c >> 5, of = c & 31;
        float4 v = *(const float4*)(rootM + k * DIM + of * 4);
        ushort4 s;
        s.x = f2b(v.x); s.y = f2b(v.y); s.z = f2b(v.z); s.w = f2b(v.w);
        *(ushort4*)&wt[k * 136 + of * 4] = s;
    }
    __syncthreads();

    int w = t >> 6, l = t & 63, n = l & 15, q = l >> 4;
    f32x4 acc[2][4] = {};
#pragma unroll
    for (int kb = 0; kb < 4; kb++) {
        bf16x8 a[4];
#pragma unroll
        for (int rt = 0; rt < 4; rt++) a[rt] = *(const bf16x8*)&xrf[((rt * 4 + kb) * 64 + l) * 8];
        int kbase = kb * 32 + q * 8;
#pragma unroll
        for (int c = 0; c < 2; c++) {
            int ob = (w * 2 + c) * 16 + n;
            bf16x8 b;
#pragma unroll
            for (int j = 0; j < 8; j++) b[j] = u2b(wt[(kbase + j) * 136 + ob]);
#pragma unroll
            for (int rt = 0; rt < 4; rt++)
                acc[c][rt] = __builtin_amdgcn_mfma_f32_16x16x32_bf16(a[rt], b, acc[c][rt], 0, 0, 0);
        }
    }
#pragma unroll
    for (int c = 0; c < 2; c++) {
        int col = (w * 2 + c) * 16 + n;
        float bo = bias[col];
#pragma unroll
        for (int rt = 0; rt < 4; rt++) {
#pragma unroll
            for (int rg = 0; rg < 4; rg++) {
                int row = n0 + rt * 16 + q * 4 + rg;
                if (row < N) {
                    float v = accbuf[(size_t)row * DIM + col] + acc[c][rt][rg] + bo;
                    if (mode) {
                        outb[(size_t)row * DIM + col] = f2b(fmaxf(v, 0.f));
                    } else {
                        outf[(size_t)row * DIM + col] = v;
                    }
                }
            }
        }
    }
}

extern "C" void kernel_launch(void* const* d_in, const int* in_sizes, int n_in,
                              void* d_out, int out_size, void* d_ws, size_t ws_size,
                              hipStream_t stream) {
    const int N = N_NODES, E = N_EDGES, R = N_REL;

    const int* entity = (const int*)d_in[0];
    const int* eidx   = (const int*)d_in[1];
    const int* src    = eidx;
    const int* dst    = eidx + E;
    const int* etype  = (const int*)d_in[2];
    const float* emb  = (const float*)d_in[3];
    const float* basis1 = (const float*)d_in[4];
    const float* att1   = (const float*)d_in[5];
    const float* w1     = (const float*)d_in[6];
    const float* root1  = (const float*)d_in[7];
    const float* bias1  = (const float*)d_in[8];
    const float* basis2 = (const float*)d_in[9];
    const float* att2   = (const float*)d_in[10];
    const float* w2     = (const float*)d_in[11];
    const float* root2  = (const float*)d_in[12];
    const float* bias2  = (const float*)d_in[13];
    float* out = (float*)d_out;

    size_t off = 0;
    auto alloc = [&](size_t bytes) -> void* {
        void* p = (char*)d_ws + off;
        off += (bytes + 255) & ~(size_t)255;
        return p;
    };
    unsigned short* W1 = (unsigned short*)alloc((size_t)R * DIM * DIM * 2);
    unsigned short* W2 = (unsigned short*)alloc((size_t)R * DIM * DIM * 2);
    unsigned short* xb = (unsigned short*)alloc((size_t)N * DIM * 2);
    unsigned short* hb = (unsigned short*)alloc((size_t)N * DIM * 2);
    // contiguous zero region: acc1 | acc2 | denom1 | denom2
    float* zreg   = (float*)alloc((size_t)(2 * N * DIM + 2 * N) * 4);
    float* acc1   = zreg;
    float* acc2   = zreg + (size_t)N * DIM;
    float* denom1 = zreg + (size_t)2 * N * DIM;
    float* denom2 = denom1 + N;
    float* alpha  = (float*)alloc((size_t)E * 4);
    int* nchunks  = (int*)alloc(256);
    int* offs     = (int*)alloc((size_t)(R + 1) * 4);
    int* eids     = (int*)alloc((size_t)E * 4);
    int* chunk_r  = (int*)alloc((size_t)MAXCH * 4);
    int* chunk_o  = (int*)alloc((size_t)MAXCH * 4);

    int zcount4 = (2 * N * DIM + 2 * N) / 4;

    // ---- prep (3 dispatches, no memsets) ----
    prep_kernel<<<2048, 256, 0, stream>>>((const float4*)emb, entity,
                                          (ushort4*)xb, (float4*)zreg, zcount4);
    plan_kernel<<<1, 512, 0, stream>>>(etype, offs, eids, chunk_r, chunk_o, nchunks);
    wmix_kernel<<<dim3(64, 16), 256, 0, stream>>>(att1, basis1, W1, att2, basis2, W2, R);

    // ---- layer 1: xb -> hb (relu, bf16) ----
    logitexp_kernel<<<E / 4, 256, 0, stream>>>(xb, w1, src, dst, etype, alpha, denom1, E);
    msg_kernel<<<MAXCH, 256, 0, stream>>>(xb, W1, chunk_r, chunk_o, nchunks,
                                          eids, offs, src, dst, alpha, denom1, acc1);
    root_kernel<<<(N + 63) / 64, 256, 0, stream>>>(xb, root1, bias1, acc1, hb, nullptr, 1, N);

    // ---- layer 2: hb -> out (fp32) ----
    logitexp_kernel<<<E / 4, 256, 0, stream>>>(hb, w2, src, dst, etype, alpha, denom2, E);
    msg_kernel<<<MAXCH, 256, 0, stream>>>(hb, W2, chunk_r, chunk_o, nchunks,
                                          eids, offs, src, dst, alpha, denom2, acc2);
    root_kernel<<<(N + 63) / 64, 256, 0, stream>>>(hb, root2, bias2, acc2, nullptr, out, 0, N);
}

// Round 12
// 249.583 us; speedup vs baseline: 1.0108x; 1.0108x over previous
//
#include <hip/hip_runtime.h>
#include <hip/hip_bf16.h>

#define N_NODES 20000
#define N_EDGES 32768
#define DIM 128
#define N_REL 474
#define N_BASIS 64
#define TILE_E 64
#define MAXCH (N_EDGES / TILE_E + N_REL)   // 986 upper bound on chunk count
#define WSTRIDE 260                         // LDS row stride (shorts) for wmix staging

typedef __bf16 bf16x8 __attribute__((ext_vector_type(8)));
typedef float f32x4 __attribute__((ext_vector_type(4)));

// ---------- helpers ----------
__device__ __forceinline__ unsigned short f2b(float f) {   // RNE fp32 -> bf16 bits
    unsigned u = __float_as_uint(f);
    unsigned r = (u + 0x7FFFu + ((u >> 16) & 1u)) >> 16;
    return (unsigned short)r;
}
__device__ __forceinline__ float b2f(unsigned short s) {
    return __uint_as_float(((unsigned)s) << 16);
}
__device__ __forceinline__ __bf16 u2b(unsigned short u) {
    union { unsigned short u; __bf16 b; } c; c.u = u; return c.b;
}

// ---------- prep: gather xb = bf16(emb[entity]) + count etype + zero acc/denom (R10-proven) ----------
__global__ __launch_bounds__(256) void prep_kernel(const float4* __restrict__ emb,
                                                   const int* __restrict__ entity,
                                                   const int* __restrict__ etype,
                                                   ushort4* __restrict__ xb4,
                                                   float4* __restrict__ zreg, int zcount4,
                                                   int* __restrict__ cnt) {
    int gtid = blockIdx.x * 256 + threadIdx.x;
    int gsz = gridDim.x * 256;
    int total4 = N_NODES * DIM / 4;
    for (int i = gtid; i < total4; i += gsz) {
        int n = i >> 5, rem = i & 31;
        float4 v = emb[(size_t)entity[n] * 32 + rem];
        ushort4 s;
        s.x = f2b(v.x); s.y = f2b(v.y); s.z = f2b(v.z); s.w = f2b(v.w);
        xb4[i] = s;
    }
    for (int e = gtid; e < N_EDGES; e += gsz) atomicAdd(&cnt[etype[e]], 1);
    float4 z = make_float4(0.f, 0.f, 0.f, 0.f);
    for (int i = gtid; i < zcount4; i += gsz) zreg[i] = z;
}

// ---------- scanr: single block scan over R + chunk emit + cursor init (R10-proven) ----------
__global__ void scanr_kernel(const int* __restrict__ cnt, int* __restrict__ offs,
                             int* __restrict__ cursor, int* __restrict__ chunk_r,
                             int* __restrict__ chunk_o, int* __restrict__ nchunks,
                             int R, int E) {
    __shared__ int s[512];
    int t = threadIdx.x;
    int v = (t < R) ? cnt[t] : 0;
    s[t] = v;
    __syncthreads();
    for (int d = 1; d < 512; d <<= 1) {
        int add = (t >= d) ? s[t - d] : 0;
        __syncthreads();
        s[t] += add;
        __syncthreads();
    }
    int excl = s[t] - v;
    if (t < R) { offs[t] = excl; cursor[t] = excl; }
    if (t == 0) offs[R] = E;
    int nc = (v + TILE_E - 1) / TILE_E;
    if (t < R && nc > 0) {
        int b = atomicAdd(nchunks, nc);
        for (int c = 0; c < nc; c++) { chunk_r[b + c] = t; chunk_o[b + c] = excl + c * TILE_E; }
    }
}

// ---------- scatlogit: scatter into relation-CSR + fused logit+exp+denom (layer 1) ----------
__global__ __launch_bounds__(256) void scatlogit_kernel(const unsigned short* __restrict__ xb,
                                                        const float* __restrict__ w,
                                                        const int* __restrict__ src,
                                                        const int* __restrict__ dst,
                                                        const int* __restrict__ et,
                                                        int* __restrict__ cursor,
                                                        int* __restrict__ eids,
                                                        float* __restrict__ alpha,
                                                        float* __restrict__ den, int E) {
    int wid = (blockIdx.x * 256 + threadIdx.x) >> 6;
    int lane = threadIdx.x & 63;
    if (wid >= E) return;
    int s = src[wid], d = dst[wid], r = et[wid];
    if (lane == 0) {
        int p = atomicAdd(&cursor[r], 1);
        eids[p] = wid;
    }
    unsigned ax = ((const unsigned*)(xb + (size_t)s * DIM))[lane];
    unsigned bx = ((const unsigned*)(xb + (size_t)d * DIM))[lane];
    float2 wv = ((const float2*)(w + (size_t)r * DIM))[lane];
    float v = b2f((unsigned short)(ax & 0xFFFF)) * wv.x * b2f((unsigned short)(bx & 0xFFFF))
            + b2f((unsigned short)(ax >> 16)) * wv.y * b2f((unsigned short)(bx >> 16));
    for (int off = 32; off > 0; off >>= 1) v += __shfl_xor(v, off, 64);
    if (lane == 0) {
        float a = expf(v);
        alpha[wid] = a;
        atomicAdd(&den[d], a);
    }
}

// ---------- fused logit + exp + denom (layer 2; R10-proven) ----------
__global__ __launch_bounds__(256) void logitexp_kernel(const unsigned short* __restrict__ xb,
                                                       const float* __restrict__ w,
                                                       const int* __restrict__ src,
                                                       const int* __restrict__ dst,
                                                       const int* __restrict__ et,
                                                       float* __restrict__ alpha,
                                                       float* __restrict__ den, int E) {
    int wid = (blockIdx.x * 256 + threadIdx.x) >> 6;
    int lane = threadIdx.x & 63;
    if (wid >= E) return;
    int s = src[wid], d = dst[wid], r = et[wid];
    unsigned ax = ((const unsigned*)(xb + (size_t)s * DIM))[lane];
    unsigned bx = ((const unsigned*)(xb + (size_t)d * DIM))[lane];
    float2 wv = ((const float2*)(w + (size_t)r * DIM))[lane];
    float v = b2f((unsigned short)(ax & 0xFFFF)) * wv.x * b2f((unsigned short)(bx & 0xFFFF))
            + b2f((unsigned short)(ax >> 16)) * wv.y * b2f((unsigned short)(bx >> 16));
    for (int off = 32; off > 0; off >>= 1) v += __shfl_xor(v, off, 64);
    if (lane == 0) {
        float a = expf(v);
        alpha[wid] = a;
        atomicAdd(&den[d], a);
    }
}

// ---------- W1+W2 = att @ basis via MFMA, both layers in one dispatch (R11-proven) ----------
__global__ __launch_bounds__(256) void wmix_kernel(const float* __restrict__ att1,
                                                   const float* __restrict__ basis1,
                                                   unsigned short* __restrict__ W1,
                                                   const float* __restrict__ att2,
                                                   const float* __restrict__ basis2,
                                                   unsigned short* __restrict__ W2, int R) {
    const float* att   = (blockIdx.y < 8) ? att1 : att2;
    const float* basis = (blockIdx.y < 8) ? basis1 : basis2;
    unsigned short* W  = (blockIdx.y < 8) ? W1 : W2;
    int io0 = blockIdx.x * 256;
    int r0 = (blockIdx.y & 7) * 64;
    __shared__ unsigned short bt[64 * WSTRIDE];
    int t = threadIdx.x;
#pragma unroll
    for (int p = 0; p < 16; p++) {
        int c = t + 256 * p;
        int k = c >> 6, of = c & 63;
        float4 v = *(const float4*)(basis + (size_t)k * (DIM * DIM) + io0 + of * 4);
        ushort4 s;
        s.x = f2b(v.x); s.y = f2b(v.y); s.z = f2b(v.z); s.w = f2b(v.w);
        *(ushort4*)&bt[k * WSTRIDE + of * 4] = s;
    }
    __syncthreads();

    int w = t >> 6, l = t & 63, n = l & 15, q = l >> 4;
    f32x4 acc[4][4] = {};                       // [rt][c]
#pragma unroll
    for (int kb = 0; kb < 2; kb++) {
        int kbase = kb * 32 + q * 8;
        bf16x8 a[4];
#pragma unroll
        for (int rt = 0; rt < 4; rt++) {
            int rm = min(r0 + rt * 16 + n, R - 1);
            const float* ap = att + (size_t)rm * N_BASIS + kbase;
#pragma unroll
            for (int j = 0; j < 8; j++) a[rt][j] = u2b(f2b(ap[j]));
        }
#pragma unroll
        for (int c = 0; c < 4; c++) {
            int ob = w * 64 + c * 16 + n;
            bf16x8 b;
#pragma unroll
            for (int j = 0; j < 8; j++) b[j] = u2b(bt[(kbase + j) * WSTRIDE + ob]);
#pragma unroll
            for (int rt = 0; rt < 4; rt++)
                acc[rt][c] = __builtin_amdgcn_mfma_f32_16x16x32_bf16(a[rt], b, acc[rt][c], 0, 0, 0);
        }
    }
#pragma unroll
    for (int rt = 0; rt < 4; rt++) {
#pragma unroll
        for (int c = 0; c < 4; c++) {
            int col = io0 + w * 64 + c * 16 + n;
#pragma unroll
            for (int rg = 0; rg < 4; rg++) {
                int r = r0 + rt * 16 + q * 4 + rg;
                if (r < R) W[(size_t)r * (DIM * DIM) + col] = f2b(acc[rt][c][rg]);
            }
        }
    }
}

// ---------- msg: per 64-edge chunk, (64x128)@(128x128) MFMA + alpha-scaled atomicAdd (R10-proven) ----------
__global__ __launch_bounds__(256) void msg_kernel(const unsigned short* __restrict__ xb,
                                                  const unsigned short* __restrict__ W,
                                                  const int* __restrict__ chunk_r,
                                                  const int* __restrict__ chunk_off,
                                                  const int* __restrict__ nchunks,
                                                  const int* __restrict__ eids,
                                                  const int* __restrict__ offs,
                                                  const int* __restrict__ src,
                                                  const int* __restrict__ dst,
                                                  const float* __restrict__ ae,
                                                  const float* __restrict__ denom,
                                                  float* __restrict__ outacc) {
    if ((int)blockIdx.x >= *nchunks) return;
    int r = chunk_r[blockIdx.x];
    int base = chunk_off[blockIdx.x];
    int nE = min(TILE_E, offs[r + 1] - base);
    const unsigned short* Wr = W + (size_t)r * (DIM * DIM);

    __shared__ unsigned short wt[128 * 136];   // [k][o] pad
    __shared__ unsigned short xjf[8192];       // A-frag order, 64 edges
    __shared__ float scf[TILE_E];
    __shared__ int sdd[TILE_E];

    int t = threadIdx.x;
    if (t < TILE_E) {
        if (t < nE) {
            int e = eids[base + t];
            int d_ = dst[e];
            sdd[t] = d_;
            scf[t] = ae[e] / denom[d_];
        } else { sdd[t] = 0; scf[t] = 0.f; }
    }
    // stage A: slot c = (rt*4+kb)*64 + q*16 + m
#pragma unroll
    for (int p = 0; p < 4; p++) {
        int c = t + 256 * p;
        int g = c >> 6;
        int rt = g >> 2, kb = g & 3;
        int q = (c >> 4) & 3, m = c & 15;
        int e = rt * 16 + m;
        int oct = kb * 4 + q;
        int4 v = make_int4(0, 0, 0, 0);
        if (e < nE)
            v = *(const int4*)(xb + (size_t)src[eids[base + e]] * DIM + oct * 8);
        *(int4*)&xjf[c * 8] = v;
    }
    // stage W tile
#pragma unroll
    for (int p = 0; p < 8; p++) {
        int c = t + 256 * p;
        int k = c >> 4, oct = c & 15;
        int4 v = *(const int4*)(Wr + k * DIM + oct * 8);
        *(int4*)&wt[k * 136 + oct * 8] = v;
    }
    __syncthreads();

    int w = t >> 6, l = t & 63, n = l & 15, q = l >> 4;
    f32x4 acc[2][4] = {};                       // [ct-local][rt]
#pragma unroll
    for (int kb = 0; kb < 4; kb++) {
        bf16x8 a[4];
#pragma unroll
        for (int rt = 0; rt < 4; rt++) a[rt] = *(const bf16x8*)&xjf[((rt * 4 + kb) * 64 + l) * 8];
        int kbase = kb * 32 + q * 8;
#pragma unroll
        for (int c = 0; c < 2; c++) {
            int ob = (w * 2 + c) * 16 + n;
            bf16x8 b;
#pragma unroll
            for (int j = 0; j < 8; j++) b[j] = u2b(wt[(kbase + j) * 136 + ob]);
#pragma unroll
            for (int rt = 0; rt < 4; rt++)
                acc[c][rt] = __builtin_amdgcn_mfma_f32_16x16x32_bf16(a[rt], b, acc[c][rt], 0, 0, 0);
        }
    }
#pragma unroll
    for (int c = 0; c < 2; c++) {
        int col = (w * 2 + c) * 16 + n;
#pragma unroll
        for (int rt = 0; rt < 4; rt++) {
#pragma unroll
            for (int rg = 0; rg < 4; rg++) {
                int e = rt * 16 + q * 4 + rg;
                if (e < nE)
                    atomicAdd(&outacc[(size_t)sdd[e] * DIM + col], scf[e] * acc[c][rt][rg]);
            }
        }
    }
}

// ---------- root: out = acc + x @ root + bias via MFMA; mode 1 = relu+bf16, 0 = fp32 (R10-proven) ----------
__global__ __launch_bounds__(256) void root_kernel(const unsigned short* __restrict__ xb,
                                                   const float* __restrict__ rootM,
                                                   const float* __restrict__ bias,
                                                   const float* __restrict__ accbuf,
                                                   unsigned short* __restrict__ outb,
                                                   float* __restrict__ outf,
                                                   int mode, int N) {
    int n0 = blockIdx.x * 64;
    __shared__ unsigned short wt[128 * 136];
    __shared__ unsigned short xrf[8192];
    int t = threadIdx.x;
#pragma unroll
    for (int p = 0; p < 4; p++) {
        int c = t + 256 * p;
        int g = c >> 6;
        int rt = g >> 2, kb = g & 3;
        int q = (c >> 4) & 3, m = c & 15;
        int row = n0 + rt * 16 + m;
        int oct = kb * 4 + q;
        int4 v = make_int4(0, 0, 0, 0);
        if (row < N) v = *(const int4*)(xb + (size_t)row * DIM + oct * 8);
        *(int4*)&xrf[c * 8] = v;
    }
#pragma unroll
    for (int p = 0; p < 16; p++) {
        int c = t + 256 * p;
        int k = c >> 5, of = c & 31;
        float4 v = *(const float4*)(rootM + k * DIM + of * 4);
        ushort4 s;
        s.x = f2b(v.x); s.y = f2b(v.y); s.z = f2b(v.z); s.w = f2b(v.w);
        *(ushort4*)&wt[k * 136 + of * 4] = s;
    }
    __syncthreads();

    int w = t >> 6, l = t & 63, n = l & 15, q = l >> 4;
    f32x4 acc[2][4] = {};
#pragma unroll
    for (int kb = 0; kb < 4; kb++) {
        bf16x8 a[4];
#pragma unroll
        for (int rt = 0; rt < 4; rt++) a[rt] = *(const bf16x8*)&xrf[((rt * 4 + kb) * 64 + l) * 8];
        int kbase = kb * 32 + q * 8;
#pragma unroll
        for (int c = 0; c < 2; c++) {
            int ob = (w * 2 + c) * 16 + n;
            bf16x8 b;
#pragma unroll
            for (int j = 0; j < 8; j++) b[j] = u2b(wt[(kbase + j) * 136 + ob]);
#pragma unroll
            for (int rt = 0; rt < 4; rt++)
                acc[c][rt] = __builtin_amdgcn_mfma_f32_16x16x32_bf16(a[rt], b, acc[c][rt], 0, 0, 0);
        }
    }
#pragma unroll
    for (int c = 0; c < 2; c++) {
        int col = (w * 2 + c) * 16 + n;
        float bo = bias[col];
#pragma unroll
        for (int rt = 0; rt < 4; rt++) {
#pragma unroll
            for (int rg = 0; rg < 4; rg++) {
                int row = n0 + rt * 16 + q * 4 + rg;
                if (row < N) {
                    float v = accbuf[(size_t)row * DIM + col] + acc[c][rt][rg] + bo;
                    if (mode) {
                        outb[(size_t)row * DIM + col] = f2b(fmaxf(v, 0.f));
                    } else {
                        outf[(size_t)row * DIM + col] = v;
                    }
                }
            }
        }
    }
}

extern "C" void kernel_launch(void* const* d_in, const int* in_sizes, int n_in,
                              void* d_out, int out_size, void* d_ws, size_t ws_size,
                              hipStream_t stream) {
    const int N = N_NODES, E = N_EDGES, R = N_REL;

    const int* entity = (const int*)d_in[0];
    const int* eidx   = (const int*)d_in[1];
    const int* src    = eidx;
    const int* dst    = eidx + E;
    const int* etype  = (const int*)d_in[2];
    const float* emb  = (const float*)d_in[3];
    const float* basis1 = (const float*)d_in[4];
    const float* att1   = (const float*)d_in[5];
    const float* w1     = (const float*)d_in[6];
    const float* root1  = (const float*)d_in[7];
    const float* bias1  = (const float*)d_in[8];
    const float* basis2 = (const float*)d_in[9];
    const float* att2   = (const float*)d_in[10];
    const float* w2     = (const float*)d_in[11];
    const float* root2  = (const float*)d_in[12];
    const float* bias2  = (const float*)d_in[13];
    float* out = (float*)d_out;

    size_t off = 0;
    auto alloc = [&](size_t bytes) -> void* {
        void* p = (char*)d_ws + off;
        off += (bytes + 255) & ~(size_t)255;
        return p;
    };
    unsigned short* W1 = (unsigned short*)alloc((size_t)R * DIM * DIM * 2);
    unsigned short* W2 = (unsigned short*)alloc((size_t)R * DIM * DIM * 2);
    unsigned short* xb = (unsigned short*)alloc((size_t)N * DIM * 2);
    unsigned short* hb = (unsigned short*)alloc((size_t)N * DIM * 2);
    // contiguous zero region: acc1 | acc2 | denom1 | denom2
    float* zreg   = (float*)alloc((size_t)(2 * N * DIM + 2 * N) * 4);
    float* acc1   = zreg;
    float* acc2   = zreg + (size_t)N * DIM;
    float* denom1 = zreg + (size_t)2 * N * DIM;
    float* denom2 = denom1 + N;
    float* alpha  = (float*)alloc((size_t)E * 4);
    int* meta     = (int*)alloc((size_t)(R + 1) * 4);   // cnt | nchunks
    int* cnt      = meta;
    int* nchunks  = meta + R;
    int* offs     = (int*)alloc((size_t)(R + 1) * 4);
    int* cursor   = (int*)alloc((size_t)R * 4);
    int* eids     = (int*)alloc((size_t)E * 4);
    int* chunk_r  = (int*)alloc((size_t)MAXCH * 4);
    int* chunk_o  = (int*)alloc((size_t)MAXCH * 4);

    int zcount4 = (2 * N * DIM + 2 * N) / 4;

    // ---- prep (3 dispatches + memset) ----
    hipMemsetAsync(meta, 0, (size_t)(R + 1) * 4, stream);
    prep_kernel<<<2048, 256, 0, stream>>>((const float4*)emb, entity, etype,
                                          (ushort4*)xb, (float4*)zreg, zcount4, cnt);
    scanr_kernel<<<1, 512, 0, stream>>>(cnt, offs, cursor, chunk_r, chunk_o, nchunks, R, E);
    wmix_kernel<<<dim3(64, 16), 256, 0, stream>>>(att1, basis1, W1, att2, basis2, W2, R);

    // ---- layer 1: xb -> hb (relu, bf16); scatter fused into logit pass ----
    scatlogit_kernel<<<E / 4, 256, 0, stream>>>(xb, w1, src, dst, etype, cursor, eids,
                                                alpha, denom1, E);
    msg_kernel<<<MAXCH, 256, 0, stream>>>(xb, W1, chunk_r, chunk_o, nchunks,
                                          eids, offs, src, dst, alpha, denom1, acc1);
    root_kernel<<<(N + 63) / 64, 256, 0, stream>>>(xb, root1, bias1, acc1, hb, nullptr, 1, N);

    // ---- layer 2: hb -> out (fp32) ----
    logitexp_kernel<<<E / 4, 256, 0, stream>>>(hb, w2, src, dst, etype, alpha, denom2, E);
    msg_kernel<<<MAXCH, 256, 0, stream>>>(hb, W2, chunk_r, chunk_o, nchunks,
                                          eids, offs, src, dst, alpha, denom2, acc2);
    root_kernel<<<(N + 63) / 64, 256, 0, stream>>>(hb, root2, bias2, acc2, nullptr, out, 0, N);
}

// Round 13
// 230.901 us; speedup vs baseline: 1.0926x; 1.0809x over previous
//
#include <hip/hip_runtime.h>
#include <hip/hip_bf16.h>

#define N_NODES 20000
#define N_EDGES 32768
#define DIM 128
#define N_REL 474
#define N_BASIS 64
#define TILE_E 64
#define MAXCH (N_EDGES / TILE_E + N_REL)   // 986 upper bound on chunk count
#define WSTRIDE 260                         // LDS row stride (shorts) for wmix staging
#define HIST_BLKS 16
#define EDGES_PER_HIST (N_EDGES / HIST_BLKS)

typedef __bf16 bf16x8 __attribute__((ext_vector_type(8)));
typedef float f32x4 __attribute__((ext_vector_type(4)));

// ---------- helpers ----------
__device__ __forceinline__ unsigned short f2b(float f) {   // RNE fp32 -> bf16 bits
    unsigned u = __float_as_uint(f);
    unsigned r = (u + 0x7FFFu + ((u >> 16) & 1u)) >> 16;
    return (unsigned short)r;
}
__device__ __forceinline__ float b2f(unsigned short s) {
    return __uint_as_float(((unsigned)s) << 16);
}
__device__ __forceinline__ __bf16 u2b(unsigned short u) {
    union { unsigned short u; __bf16 b; } c; c.u = u; return c.b;
}

// ---------- stage 0 (one dispatch): blocks 0..1023 wmix both layers;
//            blocks 1024..2047 gather + zero + partial histograms ----------
__global__ __launch_bounds__(256) void prepmix_kernel(const float4* __restrict__ emb,
                                                      const int* __restrict__ entity,
                                                      const int* __restrict__ etype,
                                                      ushort4* __restrict__ xb4,
                                                      float4* __restrict__ zreg, int zcount4,
                                                      int* __restrict__ partial,
                                                      const float* __restrict__ att1,
                                                      const float* __restrict__ basis1,
                                                      unsigned short* __restrict__ W1,
                                                      const float* __restrict__ att2,
                                                      const float* __restrict__ basis2,
                                                      unsigned short* __restrict__ W2) {
    __shared__ __align__(16) unsigned short bt[64 * WSTRIDE];
    int t = threadIdx.x;
    if (blockIdx.x < 1024) {
        // ---- wmix: W = att @ basis (R11/R12-proven body) ----
        int wi = blockIdx.x;
        const float* att   = (wi >= 512) ? att2 : att1;
        const float* basis = (wi >= 512) ? basis2 : basis1;
        unsigned short* W  = (wi >= 512) ? W2 : W1;
        int io0 = (wi & 63) * 256;
        int r0 = ((wi >> 6) & 7) * 64;
#pragma unroll
        for (int p = 0; p < 16; p++) {
            int c = t + 256 * p;
            int k = c >> 6, of = c & 63;
            float4 v = *(const float4*)(basis + (size_t)k * (DIM * DIM) + io0 + of * 4);
            ushort4 s;
            s.x = f2b(v.x); s.y = f2b(v.y); s.z = f2b(v.z); s.w = f2b(v.w);
            *(ushort4*)&bt[k * WSTRIDE + of * 4] = s;
        }
        __syncthreads();

        int w = t >> 6, l = t & 63, n = l & 15, q = l >> 4;
        f32x4 acc[4][4] = {};                   // [rt][c]
#pragma unroll
        for (int kb = 0; kb < 2; kb++) {
            int kbase = kb * 32 + q * 8;
            bf16x8 a[4];
#pragma unroll
            for (int rt = 0; rt < 4; rt++) {
                int rm = min(r0 + rt * 16 + n, N_REL - 1);
                const float* ap = att + (size_t)rm * N_BASIS + kbase;
#pragma unroll
                for (int j = 0; j < 8; j++) a[rt][j] = u2b(f2b(ap[j]));
            }
#pragma unroll
            for (int c = 0; c < 4; c++) {
                int ob = w * 64 + c * 16 + n;
                bf16x8 b;
#pragma unroll
                for (int j = 0; j < 8; j++) b[j] = u2b(bt[(kbase + j) * WSTRIDE + ob]);
#pragma unroll
                for (int rt = 0; rt < 4; rt++)
                    acc[rt][c] = __builtin_amdgcn_mfma_f32_16x16x32_bf16(a[rt], b, acc[rt][c], 0, 0, 0);
            }
        }
#pragma unroll
        for (int rt = 0; rt < 4; rt++) {
#pragma unroll
            for (int c = 0; c < 4; c++) {
                int col = io0 + w * 64 + c * 16 + n;
#pragma unroll
                for (int rg = 0; rg < 4; rg++) {
                    int r = r0 + rt * 16 + q * 4 + rg;
                    if (r < N_REL) W[(size_t)r * (DIM * DIM) + col] = f2b(acc[rt][c][rg]);
                }
            }
        }
    } else {
        // ---- prep: gather xb + zero acc/denom + partial hist (blocks 0..15 of this half) ----
        int pb = blockIdx.x - 1024;
        int gtid = pb * 256 + t;
        int gsz = 1024 * 256;
        int total4 = N_NODES * DIM / 4;
        for (int i = gtid; i < total4; i += gsz) {
            int n = i >> 5, rem = i & 31;
            float4 v = emb[(size_t)entity[n] * 32 + rem];
            ushort4 s;
            s.x = f2b(v.x); s.y = f2b(v.y); s.z = f2b(v.z); s.w = f2b(v.w);
            xb4[i] = s;
        }
        float4 z = make_float4(0.f, 0.f, 0.f, 0.f);
        for (int i = gtid; i < zcount4; i += gsz) zreg[i] = z;
        if (pb < HIST_BLKS) {
            int* ih = (int*)bt;
            for (int i = t; i < N_REL; i += 256) ih[i] = 0;
            __syncthreads();
            int e0 = pb * EDGES_PER_HIST;
            for (int e = e0 + t; e < e0 + EDGES_PER_HIST; e += 256)
                atomicAdd(&ih[etype[e]], 1);
            __syncthreads();
            for (int i = t; i < N_REL; i += 256) partial[pb * N_REL + i] = ih[i];
        }
    }
}

// ---------- scanr: sum partials + scan + chunk emit + cursor init (no pre-zeroed globals) ----------
__global__ void scanr_kernel(const int* __restrict__ partial, int* __restrict__ offs,
                             int* __restrict__ cursor, int* __restrict__ chunk_r,
                             int* __restrict__ chunk_o, int* __restrict__ nchunks) {
    __shared__ int s[512];
    __shared__ int lnc;
    int t = threadIdx.x;
    int v = 0;
    if (t < N_REL) {
#pragma unroll
        for (int k = 0; k < HIST_BLKS; k++) v += partial[k * N_REL + t];
    }
    s[t] = v;
    if (t == 0) lnc = 0;
    __syncthreads();
    for (int d = 1; d < 512; d <<= 1) {
        int add = (t >= d) ? s[t - d] : 0;
        __syncthreads();
        s[t] += add;
        __syncthreads();
    }
    int excl = s[t] - v;
    if (t < N_REL) { offs[t] = excl; cursor[t] = excl; }
    if (t == 0) offs[N_REL] = N_EDGES;
    if (t < N_REL && v > 0) {
        int nc = (v + TILE_E - 1) / TILE_E;
        int cb = atomicAdd(&lnc, nc);
        for (int c = 0; c < nc; c++) { chunk_r[cb + c] = t; chunk_o[cb + c] = excl + c * TILE_E; }
    }
    __syncthreads();
    if (t == 0) *nchunks = lnc;
}

// ---------- scatlogit: scatter into relation-CSR + fused logit+exp+denom (R12-proven) ----------
__global__ __launch_bounds__(256) void scatlogit_kernel(const unsigned short* __restrict__ xb,
                                                        const float* __restrict__ w,
                                                        const int* __restrict__ src,
                                                        const int* __restrict__ dst,
                                                        const int* __restrict__ et,
                                                        int* __restrict__ cursor,
                                                        int* __restrict__ eids,
                                                        float* __restrict__ alpha,
                                                        float* __restrict__ den, int E) {
    int wid = (blockIdx.x * 256 + threadIdx.x) >> 6;
    int lane = threadIdx.x & 63;
    if (wid >= E) return;
    int s = src[wid], d = dst[wid], r = et[wid];
    if (lane == 0) {
        int p = atomicAdd(&cursor[r], 1);
        eids[p] = wid;
    }
    unsigned ax = ((const unsigned*)(xb + (size_t)s * DIM))[lane];
    unsigned bx = ((const unsigned*)(xb + (size_t)d * DIM))[lane];
    float2 wv = ((const float2*)(w + (size_t)r * DIM))[lane];
    float v = b2f((unsigned short)(ax & 0xFFFF)) * wv.x * b2f((unsigned short)(bx & 0xFFFF))
            + b2f((unsigned short)(ax >> 16)) * wv.y * b2f((unsigned short)(bx >> 16));
    for (int off = 32; off > 0; off >>= 1) v += __shfl_xor(v, off, 64);
    if (lane == 0) {
        float a = expf(v);
        alpha[wid] = a;
        atomicAdd(&den[d], a);
    }
}

// ---------- fused logit + exp + denom (layer 2; R10-proven) ----------
__global__ __launch_bounds__(256) void logitexp_kernel(const unsigned short* __restrict__ xb,
                                                       const float* __restrict__ w,
                                                       const int* __restrict__ src,
                                                       const int* __restrict__ dst,
                                                       const int* __restrict__ et,
                                                       float* __restrict__ alpha,
                                                       float* __restrict__ den, int E) {
    int wid = (blockIdx.x * 256 + threadIdx.x) >> 6;
    int lane = threadIdx.x & 63;
    if (wid >= E) return;
    int s = src[wid], d = dst[wid], r = et[wid];
    unsigned ax = ((const unsigned*)(xb + (size_t)s * DIM))[lane];
    unsigned bx = ((const unsigned*)(xb + (size_t)d * DIM))[lane];
    float2 wv = ((const float2*)(w + (size_t)r * DIM))[lane];
    float v = b2f((unsigned short)(ax & 0xFFFF)) * wv.x * b2f((unsigned short)(bx & 0xFFFF))
            + b2f((unsigned short)(ax >> 16)) * wv.y * b2f((unsigned short)(bx >> 16));
    for (int off = 32; off > 0; off >>= 1) v += __shfl_xor(v, off, 64);
    if (lane == 0) {
        float a = expf(v);
        alpha[wid] = a;
        atomicAdd(&den[d], a);
    }
}

// ---------- msg: per 64-edge chunk, (64x128)@(128x128) MFMA + alpha-scaled atomicAdd (R10-proven) ----------
__global__ __launch_bounds__(256) void msg_kernel(const unsigned short* __restrict__ xb,
                                                  const unsigned short* __restrict__ W,
                                                  const int* __restrict__ chunk_r,
                                                  const int* __restrict__ chunk_off,
                                                  const int* __restrict__ nchunks,
                                                  const int* __restrict__ eids,
                                                  const int* __restrict__ offs,
                                                  const int* __restrict__ src,
                                                  const int* __restrict__ dst,
                                                  const float* __restrict__ ae,
                                                  const float* __restrict__ denom,
                                                  float* __restrict__ outacc) {
    if ((int)blockIdx.x >= *nchunks) return;
    int r = chunk_r[blockIdx.x];
    int base = chunk_off[blockIdx.x];
    int nE = min(TILE_E, offs[r + 1] - base);
    const unsigned short* Wr = W + (size_t)r * (DIM * DIM);

    __shared__ unsigned short wt[128 * 136];   // [k][o] pad
    __shared__ unsigned short xjf[8192];       // A-frag order, 64 edges
    __shared__ float scf[TILE_E];
    __shared__ int sdd[TILE_E];

    int t = threadIdx.x;
    if (t < TILE_E) {
        if (t < nE) {
            int e = eids[base + t];
            int d_ = dst[e];
            sdd[t] = d_;
            scf[t] = ae[e] / denom[d_];
        } else { sdd[t] = 0; scf[t] = 0.f; }
    }
    // stage A: slot c = (rt*4+kb)*64 + q*16 + m
#pragma unroll
    for (int p = 0; p < 4; p++) {
        int c = t + 256 * p;
        int g = c >> 6;
        int rt = g >> 2, kb = g & 3;
        int q = (c >> 4) & 3, m = c & 15;
        int e = rt * 16 + m;
        int oct = kb * 4 + q;
        int4 v = make_int4(0, 0, 0, 0);
        if (e < nE)
            v = *(const int4*)(xb + (size_t)src[eids[base + e]] * DIM + oct * 8);
        *(int4*)&xjf[c * 8] = v;
    }
    // stage W tile
#pragma unroll
    for (int p = 0; p < 8; p++) {
        int c = t + 256 * p;
        int k = c >> 4, oct = c & 15;
        int4 v = *(const int4*)(Wr + k * DIM + oct * 8);
        *(int4*)&wt[k * 136 + oct * 8] = v;
    }
    __syncthreads();

    int w = t >> 6, l = t & 63, n = l & 15, q = l >> 4;
    f32x4 acc[2][4] = {};                       // [ct-local][rt]
#pragma unroll
    for (int kb = 0; kb < 4; kb++) {
        bf16x8 a[4];
#pragma unroll
        for (int rt = 0; rt < 4; rt++) a[rt] = *(const bf16x8*)&xjf[((rt * 4 + kb) * 64 + l) * 8];
        int kbase = kb * 32 + q * 8;
#pragma unroll
        for (int c = 0; c < 2; c++) {
            int ob = (w * 2 + c) * 16 + n;
            bf16x8 b;
#pragma unroll
            for (int j = 0; j < 8; j++) b[j] = u2b(wt[(kbase + j) * 136 + ob]);
#pragma unroll
            for (int rt = 0; rt < 4; rt++)
                acc[c][rt] = __builtin_amdgcn_mfma_f32_16x16x32_bf16(a[rt], b, acc[c][rt], 0, 0, 0);
        }
    }
#pragma unroll
    for (int c = 0; c < 2; c++) {
        int col = (w * 2 + c) * 16 + n;
#pragma unroll
        for (int rt = 0; rt < 4; rt++) {
#pragma unroll
            for (int rg = 0; rg < 4; rg++) {
                int e = rt * 16 + q * 4 + rg;
                if (e < nE)
                    atomicAdd(&outacc[(size_t)sdd[e] * DIM + col], scf[e] * acc[c][rt][rg]);
            }
        }
    }
}

// ---------- root: out = acc + x @ root + bias via MFMA; mode 1 = relu+bf16, 0 = fp32 (R10-proven) ----------
__global__ __launch_bounds__(256) void root_kernel(const unsigned short* __restrict__ xb,
                                                   const float* __restrict__ rootM,
                                                   const float* __restrict__ bias,
                                                   const float* __restrict__ accbuf,
                                                   unsigned short* __restrict__ outb,
                                                   float* __restrict__ outf,
                                                   int mode, int N) {
    int n0 = blockIdx.x * 64;
    __shared__ unsigned short wt[128 * 136];
    __shared__ unsigned short xrf[8192];
    int t = threadIdx.x;
#pragma unroll
    for (int p = 0; p < 4; p++) {
        int c = t + 256 * p;
        int g = c >> 6;
        int rt = g >> 2, kb = g & 3;
        int q = (c >> 4) & 3, m = c & 15;
        int row = n0 + rt * 16 + m;
        int oct = kb * 4 + q;
        int4 v = make_int4(0, 0, 0, 0);
        if (row < N) v = *(const int4*)(xb + (size_t)row * DIM + oct * 8);
        *(int4*)&xrf[c * 8] = v;
    }
#pragma unroll
    for (int p = 0; p < 16; p++) {
        int c = t + 256 * p;
        int k = c >> 5, of = c & 31;
        float4 v = *(const float4*)(rootM + k * DIM + of * 4);
        ushort4 s;
        s.x = f2b(v.x); s.y = f2b(v.y); s.z = f2b(v.z); s.w = f2b(v.w);
        *(ushort4*)&wt[k * 136 + of * 4] = s;
    }
    __syncthreads();

    int w = t >> 6, l = t & 63, n = l & 15, q = l >> 4;
    f32x4 acc[2][4] = {};
#pragma unroll
    for (int kb = 0; kb < 4; kb++) {
        bf16x8 a[4];
#pragma unroll
        for (int rt = 0; rt < 4; rt++) a[rt] = *(const bf16x8*)&xrf[((rt * 4 + kb) * 64 + l) * 8];
        int kbase = kb * 32 + q * 8;
#pragma unroll
        for (int c = 0; c < 2; c++) {
            int ob = (w * 2 + c) * 16 + n;
            bf16x8 b;
#pragma unroll
            for (int j = 0; j < 8; j++) b[j] = u2b(wt[(kbase + j) * 136 + ob]);
#pragma unroll
            for (int rt = 0; rt < 4; rt++)
                acc[c][rt] = __builtin_amdgcn_mfma_f32_16x16x32_bf16(a[rt], b, acc[c][rt], 0, 0, 0);
        }
    }
#pragma unroll
    for (int c = 0; c < 2; c++) {
        int col = (w * 2 + c) * 16 + n;
        float bo = bias[col];
#pragma unroll
        for (int rt = 0; rt < 4; rt++) {
#pragma unroll
            for (int rg = 0; rg < 4; rg++) {
                int row = n0 + rt * 16 + q * 4 + rg;
                if (row < N) {
                    float v = accbuf[(size_t)row * DIM + col] + acc[c][rt][rg] + bo;
                    if (mode) {
                        outb[(size_t)row * DIM + col] = f2b(fmaxf(v, 0.f));
                    } else {
                        outf[(size_t)row * DIM + col] = v;
                    }
                }
            }
        }
    }
}

extern "C" void kernel_launch(void* const* d_in, const int* in_sizes, int n_in,
                              void* d_out, int out_size, void* d_ws, size_t ws_size,
                              hipStream_t stream) {
    const int N = N_NODES, E = N_EDGES, R = N_REL;

    const int* entity = (const int*)d_in[0];
    const int* eidx   = (const int*)d_in[1];
    const int* src    = eidx;
    const int* dst    = eidx + E;
    const int* etype  = (const int*)d_in[2];
    const float* emb  = (const float*)d_in[3];
    const float* basis1 = (const float*)d_in[4];
    const float* att1   = (const float*)d_in[5];
    const float* w1     = (const float*)d_in[6];
    const float* root1  = (const float*)d_in[7];
    const float* bias1  = (const float*)d_in[8];
    const float* basis2 = (const float*)d_in[9];
    const float* att2   = (const float*)d_in[10];
    const float* w2     = (const float*)d_in[11];
    const float* root2  = (const float*)d_in[12];
    const float* bias2  = (const float*)d_in[13];
    float* out = (float*)d_out;

    size_t off = 0;
    auto alloc = [&](size_t bytes) -> void* {
        void* p = (char*)d_ws + off;
        off += (bytes + 255) & ~(size_t)255;
        return p;
    };
    unsigned short* W1 = (unsigned short*)alloc((size_t)R * DIM * DIM * 2);
    unsigned short* W2 = (unsigned short*)alloc((size_t)R * DIM * DIM * 2);
    unsigned short* xb = (unsigned short*)alloc((size_t)N * DIM * 2);
    unsigned short* hb = (unsigned short*)alloc((size_t)N * DIM * 2);
    // contiguous zero region: acc1 | acc2 | denom1 | denom2
    float* zreg   = (float*)alloc((size_t)(2 * N * DIM + 2 * N) * 4);
    float* acc1   = zreg;
    float* acc2   = zreg + (size_t)N * DIM;
    float* denom1 = zreg + (size_t)2 * N * DIM;
    float* denom2 = denom1 + N;
    float* alpha  = (float*)alloc((size_t)E * 4);
    int* partial  = (int*)alloc((size_t)HIST_BLKS * R * 4);
    int* nchunks  = (int*)alloc(256);
    int* offs     = (int*)alloc((size_t)(R + 1) * 4);
    int* cursor   = (int*)alloc((size_t)R * 4);
    int* eids     = (int*)alloc((size_t)E * 4);
    int* chunk_r  = (int*)alloc((size_t)MAXCH * 4);
    int* chunk_o  = (int*)alloc((size_t)MAXCH * 4);

    int zcount4 = (2 * N * DIM + 2 * N) / 4;

    // ---- stage 0: wmix(both) + gather + zero + partial hist (one dispatch, no memset) ----
    prepmix_kernel<<<2048, 256, 0, stream>>>((const float4*)emb, entity, etype,
                                             (ushort4*)xb, (float4*)zreg, zcount4, partial,
                                             att1, basis1, W1, att2, basis2, W2);
    // ---- stage 1: plan ----
    scanr_kernel<<<1, 512, 0, stream>>>(partial, offs, cursor, chunk_r, chunk_o, nchunks);

    // ---- layer 1: xb -> hb (relu, bf16) ----
    scatlogit_kernel<<<E / 4, 256, 0, stream>>>(xb, w1, src, dst, etype, cursor, eids,
                                                alpha, denom1, E);
    msg_kernel<<<MAXCH, 256, 0, stream>>>(xb, W1, chunk_r, chunk_o, nchunks,
                                          eids, offs, src, dst, alpha, denom1, acc1);
    root_kernel<<<(N + 63) / 64, 256, 0, stream>>>(xb, root1, bias1, acc1, hb, nullptr, 1, N);

    // ---- layer 2: hb -> out (fp32) ----
    logitexp_kernel<<<E / 4, 256, 0, stream>>>(hb, w2, src, dst, etype, alpha, denom2, E);
    msg_kernel<<<MAXCH, 256, 0, stream>>>(hb, W2, chunk_r, chunk_o, nchunks,
                                          eids, offs, src, dst, alpha, denom2, acc2);
    root_kernel<<<(N + 63) / 64, 256, 0, stream>>>(hb, root2, bias2, acc2, nullptr, out, 0, N);
}

// Round 14
// 225.514 us; speedup vs baseline: 1.1187x; 1.0239x over previous
//
#include <hip/hip_runtime.h>
#include <hip/hip_bf16.h>

#define N_NODES 20000
#define N_EDGES 32768
#define DIM 128
#define N_REL 474
#define N_BASIS 64
#define TILE_E 64
#define MAXCH (N_EDGES / TILE_E + N_REL)   // 986 upper bound on chunk count
#define WSTRIDE 260                         // LDS row stride (shorts) for wmix staging
#define HIST_BLKS 16
#define EDGES_PER_HIST (N_EDGES / HIST_BLKS)
#define LOGIT_BLKS (N_EDGES / 4)            // 8192
#define ROOT_BLKS ((N_NODES + 63) / 64)     // 313

typedef __bf16 bf16x8 __attribute__((ext_vector_type(8)));
typedef float f32x4 __attribute__((ext_vector_type(4)));

// ---------- helpers ----------
__device__ __forceinline__ unsigned short f2b(float f) {   // RNE fp32 -> bf16 bits
    unsigned u = __float_as_uint(f);
    unsigned r = (u + 0x7FFFu + ((u >> 16) & 1u)) >> 16;
    return (unsigned short)r;
}
__device__ __forceinline__ float b2f(unsigned short s) {
    return __uint_as_float(((unsigned)s) << 16);
}
__device__ __forceinline__ __bf16 u2b(unsigned short u) {
    union { unsigned short u; __bf16 b; } c; c.u = u; return c.b;
}

// ---------- stage 0 (one dispatch): blocks 0..1023 wmix both layers;
//            blocks 1024..2047 gather + zero denoms + partial histograms (R13-proven) ----------
__global__ __launch_bounds__(256) void prepmix_kernel(const float4* __restrict__ emb,
                                                      const int* __restrict__ entity,
                                                      const int* __restrict__ etype,
                                                      ushort4* __restrict__ xb4,
                                                      float4* __restrict__ zreg, int zcount4,
                                                      int* __restrict__ partial,
                                                      const float* __restrict__ att1,
                                                      const float* __restrict__ basis1,
                                                      unsigned short* __restrict__ W1,
                                                      const float* __restrict__ att2,
                                                      const float* __restrict__ basis2,
                                                      unsigned short* __restrict__ W2) {
    __shared__ __align__(16) unsigned short bt[64 * WSTRIDE];
    int t = threadIdx.x;
    if (blockIdx.x < 1024) {
        int wi = blockIdx.x;
        const float* att   = (wi >= 512) ? att2 : att1;
        const float* basis = (wi >= 512) ? basis2 : basis1;
        unsigned short* W  = (wi >= 512) ? W2 : W1;
        int io0 = (wi & 63) * 256;
        int r0 = ((wi >> 6) & 7) * 64;
#pragma unroll
        for (int p = 0; p < 16; p++) {
            int c = t + 256 * p;
            int k = c >> 6, of = c & 63;
            float4 v = *(const float4*)(basis + (size_t)k * (DIM * DIM) + io0 + of * 4);
            ushort4 s;
            s.x = f2b(v.x); s.y = f2b(v.y); s.z = f2b(v.z); s.w = f2b(v.w);
            *(ushort4*)&bt[k * WSTRIDE + of * 4] = s;
        }
        __syncthreads();

        int w = t >> 6, l = t & 63, n = l & 15, q = l >> 4;
        f32x4 acc[4][4] = {};                   // [rt][c]
#pragma unroll
        for (int kb = 0; kb < 2; kb++) {
            int kbase = kb * 32 + q * 8;
            bf16x8 a[4];
#pragma unroll
            for (int rt = 0; rt < 4; rt++) {
                int rm = min(r0 + rt * 16 + n, N_REL - 1);
                const float* ap = att + (size_t)rm * N_BASIS + kbase;
#pragma unroll
                for (int j = 0; j < 8; j++) a[rt][j] = u2b(f2b(ap[j]));
            }
#pragma unroll
            for (int c = 0; c < 4; c++) {
                int ob = w * 64 + c * 16 + n;
                bf16x8 b;
#pragma unroll
                for (int j = 0; j < 8; j++) b[j] = u2b(bt[(kbase + j) * WSTRIDE + ob]);
#pragma unroll
                for (int rt = 0; rt < 4; rt++)
                    acc[rt][c] = __builtin_amdgcn_mfma_f32_16x16x32_bf16(a[rt], b, acc[rt][c], 0, 0, 0);
            }
        }
#pragma unroll
        for (int rt = 0; rt < 4; rt++) {
#pragma unroll
            for (int c = 0; c < 4; c++) {
                int col = io0 + w * 64 + c * 16 + n;
#pragma unroll
                for (int rg = 0; rg < 4; rg++) {
                    int r = r0 + rt * 16 + q * 4 + rg;
                    if (r < N_REL) W[(size_t)r * (DIM * DIM) + col] = f2b(acc[rt][c][rg]);
                }
            }
        }
    } else {
        int pb = blockIdx.x - 1024;
        int gtid = pb * 256 + t;
        int gsz = 1024 * 256;
        int total4 = N_NODES * DIM / 4;
        for (int i = gtid; i < total4; i += gsz) {
            int n = i >> 5, rem = i & 31;
            float4 v = emb[(size_t)entity[n] * 32 + rem];
            ushort4 s;
            s.x = f2b(v.x); s.y = f2b(v.y); s.z = f2b(v.z); s.w = f2b(v.w);
            xb4[i] = s;
        }
        float4 z = make_float4(0.f, 0.f, 0.f, 0.f);
        for (int i = gtid; i < zcount4; i += gsz) zreg[i] = z;
        if (pb < HIST_BLKS) {
            int* ih = (int*)bt;
            for (int i = t; i < N_REL; i += 256) ih[i] = 0;
            __syncthreads();
            int e0 = pb * EDGES_PER_HIST;
            for (int e = e0 + t; e < e0 + EDGES_PER_HIST; e += 256)
                atomicAdd(&ih[etype[e]], 1);
            __syncthreads();
            for (int i = t; i < N_REL; i += 256) partial[pb * N_REL + i] = ih[i];
        }
    }
}

// ---------- scanr: sum partials + scan + chunk emit + cursor init (R13-proven) ----------
__global__ void scanr_kernel(const int* __restrict__ partial, int* __restrict__ offs,
                             int* __restrict__ cursor, int* __restrict__ chunk_r,
                             int* __restrict__ chunk_o, int* __restrict__ nchunks) {
    __shared__ int s[512];
    __shared__ int lnc;
    int t = threadIdx.x;
    int v = 0;
    if (t < N_REL) {
#pragma unroll
        for (int k = 0; k < HIST_BLKS; k++) v += partial[k * N_REL + t];
    }
    s[t] = v;
    if (t == 0) lnc = 0;
    __syncthreads();
    for (int d = 1; d < 512; d <<= 1) {
        int add = (t >= d) ? s[t - d] : 0;
        __syncthreads();
        s[t] += add;
        __syncthreads();
    }
    int excl = s[t] - v;
    if (t < N_REL) { offs[t] = excl; cursor[t] = excl; }
    if (t == 0) offs[N_REL] = N_EDGES;
    if (t < N_REL && v > 0) {
        int nc = (v + TILE_E - 1) / TILE_E;
        int cb = atomicAdd(&lnc, nc);
        for (int c = 0; c < nc; c++) { chunk_r[cb + c] = t; chunk_o[cb + c] = excl + c * TILE_E; }
    }
    __syncthreads();
    if (t == 0) *nchunks = lnc;
}

// ---------- fused: blocks [0,LOGIT_BLKS) logit(+optional scatter)+exp+denom;
//            blocks [LOGIT_BLKS, +ROOT_BLKS) rootgemm: target = x@rootM + bias ----------
__global__ __launch_bounds__(256) void fused_kernel(const unsigned short* __restrict__ xb,
                                                    const float* __restrict__ w,
                                                    const int* __restrict__ src,
                                                    const int* __restrict__ dst,
                                                    const int* __restrict__ et,
                                                    int* __restrict__ cursor,
                                                    int* __restrict__ eids,
                                                    int do_scatter,
                                                    float* __restrict__ alpha,
                                                    float* __restrict__ den,
                                                    const float* __restrict__ rootM,
                                                    const float* __restrict__ bias,
                                                    float* __restrict__ target) {
    __shared__ __align__(16) unsigned short xrf[8192];   // 16 KB: A-frags for rootgemm blocks
    int t = threadIdx.x;
    if (blockIdx.x < LOGIT_BLKS) {
        // ---- logit + exp + denom (+ scatter), R12/R13-proven body ----
        int wid = (blockIdx.x * 256 + t) >> 6;
        int lane = t & 63;
        int s = src[wid], d = dst[wid], r = et[wid];
        if (do_scatter && lane == 0) {
            int p = atomicAdd(&cursor[r], 1);
            eids[p] = wid;
        }
        unsigned ax = ((const unsigned*)(xb + (size_t)s * DIM))[lane];
        unsigned bx = ((const unsigned*)(xb + (size_t)d * DIM))[lane];
        float2 wv = ((const float2*)(w + (size_t)r * DIM))[lane];
        float v = b2f((unsigned short)(ax & 0xFFFF)) * wv.x * b2f((unsigned short)(bx & 0xFFFF))
                + b2f((unsigned short)(ax >> 16)) * wv.y * b2f((unsigned short)(bx >> 16));
        for (int off = 32; off > 0; off >>= 1) v += __shfl_xor(v, off, 64);
        if (lane == 0) {
            float a = expf(v);
            alpha[wid] = a;
            atomicAdd(&den[d], a);
        }
    } else {
        // ---- rootgemm: target[row][col] = (x @ rootM)[row][col] + bias[col] ----
        int n0 = (blockIdx.x - LOGIT_BLKS) * 64;
        // stage 64 x rows in A-frag order (R13 root staging, proven)
#pragma unroll
        for (int p = 0; p < 4; p++) {
            int c = t + 256 * p;
            int g = c >> 6;
            int rt = g >> 2, kb = g & 3;
            int q = (c >> 4) & 3, m = c & 15;
            int row = n0 + rt * 16 + m;
            int oct = kb * 4 + q;
            int4 v = make_int4(0, 0, 0, 0);
            if (row < N_NODES) v = *(const int4*)(xb + (size_t)row * DIM + oct * 8);
            *(int4*)&xrf[c * 8] = v;
        }
        __syncthreads();

        int w_ = t >> 6, l = t & 63, n = l & 15, q = l >> 4;
        f32x4 acc[2][4] = {};
#pragma unroll
        for (int kb = 0; kb < 4; kb++) {
            bf16x8 a[4];
#pragma unroll
            for (int rt = 0; rt < 4; rt++) a[rt] = *(const bf16x8*)&xrf[((rt * 4 + kb) * 64 + l) * 8];
            int kbase = kb * 32 + q * 8;
#pragma unroll
            for (int c = 0; c < 2; c++) {
                int col = (w_ * 2 + c) * 16 + n;
                // B-frag straight from L2-hot rootM (fp32 -> bf16 on the fly)
                bf16x8 b;
#pragma unroll
                for (int j = 0; j < 8; j++) b[j] = u2b(f2b(rootM[(kbase + j) * DIM + col]));
#pragma unroll
                for (int rt = 0; rt < 4; rt++)
                    acc[c][rt] = __builtin_amdgcn_mfma_f32_16x16x32_bf16(a[rt], b, acc[c][rt], 0, 0, 0);
            }
        }
#pragma unroll
        for (int c = 0; c < 2; c++) {
            int col = (w_ * 2 + c) * 16 + n;
            float bo = bias[col];
#pragma unroll
            for (int rt = 0; rt < 4; rt++) {
#pragma unroll
                for (int rg = 0; rg < 4; rg++) {
                    int row = n0 + rt * 16 + q * 4 + rg;
                    if (row < N_NODES)
                        target[(size_t)row * DIM + col] = acc[c][rt][rg] + bo;
                }
            }
        }
    }
}

// ---------- msg: per 64-edge chunk, (64x128)@(128x128) MFMA + alpha-scaled atomicAdd (R10-proven) ----------
__global__ __launch_bounds__(256) void msg_kernel(const unsigned short* __restrict__ xb,
                                                  const unsigned short* __restrict__ W,
                                                  const int* __restrict__ chunk_r,
                                                  const int* __restrict__ chunk_off,
                                                  const int* __restrict__ nchunks,
                                                  const int* __restrict__ eids,
                                                  const int* __restrict__ offs,
                                                  const int* __restrict__ src,
                                                  const int* __restrict__ dst,
                                                  const float* __restrict__ ae,
                                                  const float* __restrict__ denom,
                                                  float* __restrict__ outacc) {
    if ((int)blockIdx.x >= *nchunks) return;
    int r = chunk_r[blockIdx.x];
    int base = chunk_off[blockIdx.x];
    int nE = min(TILE_E, offs[r + 1] - base);
    const unsigned short* Wr = W + (size_t)r * (DIM * DIM);

    __shared__ unsigned short wt[128 * 136];   // [k][o] pad
    __shared__ unsigned short xjf[8192];       // A-frag order, 64 edges
    __shared__ float scf[TILE_E];
    __shared__ int sdd[TILE_E];

    int t = threadIdx.x;
    if (t < TILE_E) {
        if (t < nE) {
            int e = eids[base + t];
            int d_ = dst[e];
            sdd[t] = d_;
            scf[t] = ae[e] / denom[d_];
        } else { sdd[t] = 0; scf[t] = 0.f; }
    }
#pragma unroll
    for (int p = 0; p < 4; p++) {
        int c = t + 256 * p;
        int g = c >> 6;
        int rt = g >> 2, kb = g & 3;
        int q = (c >> 4) & 3, m = c & 15;
        int e = rt * 16 + m;
        int oct = kb * 4 + q;
        int4 v = make_int4(0, 0, 0, 0);
        if (e < nE)
            v = *(const int4*)(xb + (size_t)src[eids[base + e]] * DIM + oct * 8);
        *(int4*)&xjf[c * 8] = v;
    }
#pragma unroll
    for (int p = 0; p < 8; p++) {
        int c = t + 256 * p;
        int k = c >> 4, oct = c & 15;
        int4 v = *(const int4*)(Wr + k * DIM + oct * 8);
        *(int4*)&wt[k * 136 + oct * 8] = v;
    }
    __syncthreads();

    int w = t >> 6, l = t & 63, n = l & 15, q = l >> 4;
    f32x4 acc[2][4] = {};                       // [ct-local][rt]
#pragma unroll
    for (int kb = 0; kb < 4; kb++) {
        bf16x8 a[4];
#pragma unroll
        for (int rt = 0; rt < 4; rt++) a[rt] = *(const bf16x8*)&xjf[((rt * 4 + kb) * 64 + l) * 8];
        int kbase = kb * 32 + q * 8;
#pragma unroll
        for (int c = 0; c < 2; c++) {
            int ob = (w * 2 + c) * 16 + n;
            bf16x8 b;
#pragma unroll
            for (int j = 0; j < 8; j++) b[j] = u2b(wt[(kbase + j) * 136 + ob]);
#pragma unroll
            for (int rt = 0; rt < 4; rt++)
                acc[c][rt] = __builtin_amdgcn_mfma_f32_16x16x32_bf16(a[rt], b, acc[c][rt], 0, 0, 0);
        }
    }
#pragma unroll
    for (int c = 0; c < 2; c++) {
        int col = (w * 2 + c) * 16 + n;
#pragma unroll
        for (int rt = 0; rt < 4; rt++) {
#pragma unroll
            for (int rg = 0; rg < 4; rg++) {
                int e = rt * 16 + q * 4 + rg;
                if (e < nE)
                    atomicAdd(&outacc[(size_t)sdd[e] * DIM + col], scf[e] * acc[c][rt][rg]);
            }
        }
    }
}

// ---------- relucast: hb = bf16(relu(acc1)) ----------
__global__ __launch_bounds__(256) void relucast_kernel(const float4* __restrict__ acc,
                                                       ushort4* __restrict__ hb) {
    int i = blockIdx.x * 256 + threadIdx.x;   // grid sized exactly N*DIM/4
    float4 v = acc[i];
    ushort4 s;
    s.x = f2b(fmaxf(v.x, 0.f));
    s.y = f2b(fmaxf(v.y, 0.f));
    s.z = f2b(fmaxf(v.z, 0.f));
    s.w = f2b(fmaxf(v.w, 0.f));
    hb[i] = s;
}

extern "C" void kernel_launch(void* const* d_in, const int* in_sizes, int n_in,
                              void* d_out, int out_size, void* d_ws, size_t ws_size,
                              hipStream_t stream) {
    const int N = N_NODES, E = N_EDGES, R = N_REL;

    const int* entity = (const int*)d_in[0];
    const int* eidx   = (const int*)d_in[1];
    const int* src    = eidx;
    const int* dst    = eidx + E;
    const int* etype  = (const int*)d_in[2];
    const float* emb  = (const float*)d_in[3];
    const float* basis1 = (const float*)d_in[4];
    const float* att1   = (const float*)d_in[5];
    const float* w1     = (const float*)d_in[6];
    const float* root1  = (const float*)d_in[7];
    const float* bias1  = (const float*)d_in[8];
    const float* basis2 = (const float*)d_in[9];
    const float* att2   = (const float*)d_in[10];
    const float* w2     = (const float*)d_in[11];
    const float* root2  = (const float*)d_in[12];
    const float* bias2  = (const float*)d_in[13];
    float* out = (float*)d_out;

    size_t off = 0;
    auto alloc = [&](size_t bytes) -> void* {
        void* p = (char*)d_ws + off;
        off += (bytes + 255) & ~(size_t)255;
        return p;
    };
    unsigned short* W1 = (unsigned short*)alloc((size_t)R * DIM * DIM * 2);
    unsigned short* W2 = (unsigned short*)alloc((size_t)R * DIM * DIM * 2);
    unsigned short* xb = (unsigned short*)alloc((size_t)N * DIM * 2);
    unsigned short* hb = (unsigned short*)alloc((size_t)N * DIM * 2);
    float* acc1   = (float*)alloc((size_t)N * DIM * 4);
    // zero region: denom1 | denom2 only (acc zeroing no longer needed)
    float* zreg   = (float*)alloc((size_t)2 * N * 4);
    float* denom1 = zreg;
    float* denom2 = zreg + N;
    float* alpha  = (float*)alloc((size_t)E * 4);
    int* partial  = (int*)alloc((size_t)HIST_BLKS * R * 4);
    int* nchunks  = (int*)alloc(256);
    int* offs     = (int*)alloc((size_t)(R + 1) * 4);
    int* cursor   = (int*)alloc((size_t)R * 4);
    int* eids     = (int*)alloc((size_t)E * 4);
    int* chunk_r  = (int*)alloc((size_t)MAXCH * 4);
    int* chunk_o  = (int*)alloc((size_t)MAXCH * 4);

    int zcount4 = 2 * N / 4;

    // ---- stage 0: wmix(both) + gather + zero denoms + partial hist ----
    prepmix_kernel<<<2048, 256, 0, stream>>>((const float4*)emb, entity, etype,
                                             (ushort4*)xb, (float4*)zreg, zcount4, partial,
                                             att1, basis1, W1, att2, basis2, W2);
    // ---- stage 1: plan ----
    scanr_kernel<<<1, 512, 0, stream>>>(partial, offs, cursor, chunk_r, chunk_o, nchunks);

    // ---- layer 1: xb -> hb ----
    fused_kernel<<<LOGIT_BLKS + ROOT_BLKS, 256, 0, stream>>>(
        xb, w1, src, dst, etype, cursor, eids, 1, alpha, denom1, root1, bias1, acc1);
    msg_kernel<<<MAXCH, 256, 0, stream>>>(xb, W1, chunk_r, chunk_o, nchunks,
                                          eids, offs, src, dst, alpha, denom1, acc1);
    relucast_kernel<<<N * DIM / 4 / 256, 256, 0, stream>>>((const float4*)acc1, (ushort4*)hb);

    // ---- layer 2: hb -> out (fp32, msg adds directly onto rootgemm output) ----
    fused_kernel<<<LOGIT_BLKS + ROOT_BLKS, 256, 0, stream>>>(
        hb, w2, src, dst, etype, cursor, eids, 0, alpha, denom2, root2, bias2, out);
    msg_kernel<<<MAXCH, 256, 0, stream>>>(hb, W2, chunk_r, chunk_o, nchunks,
                                          eids, offs, src, dst, alpha, denom2, out);
}

// Round 15
// 224.832 us; speedup vs baseline: 1.1220x; 1.0030x over previous
//
#include <hip/hip_runtime.h>
#include <hip/hip_bf16.h>

#define N_NODES 20000
#define N_EDGES 32768
#define DIM 128
#define N_REL 474
#define N_BASIS 64
#define TILE_E 64
#define MAXCH (N_EDGES / TILE_E + N_REL)   // 986 upper bound on chunk count
#define WSTRIDE 260                         // LDS row stride (shorts) for wmix staging
#define HIST_BLKS 16
#define EDGES_PER_HIST (N_EDGES / HIST_BLKS)
#define LOGIT_BLKS (N_EDGES / 4)            // 8192
#define ROOT_BLKS ((N_NODES + 63) / 64)     // 313

typedef __bf16 bf16x8 __attribute__((ext_vector_type(8)));
typedef float f32x4 __attribute__((ext_vector_type(4)));

// ---------- helpers ----------
__device__ __forceinline__ unsigned short f2b(float f) {   // RNE fp32 -> bf16 bits
    unsigned u = __float_as_uint(f);
    unsigned r = (u + 0x7FFFu + ((u >> 16) & 1u)) >> 16;
    return (unsigned short)r;
}
__device__ __forceinline__ float b2f(unsigned short s) {
    return __uint_as_float(((unsigned)s) << 16);
}
__device__ __forceinline__ __bf16 u2b(unsigned short u) {
    union { unsigned short u; __bf16 b; } c; c.u = u; return c.b;
}
// pack 8 fp32 (relu) -> int4 of bf16
__device__ __forceinline__ int4 packrelu8(float4 a0, float4 a1) {
    int4 v;
    v.x = (int)((unsigned)f2b(fmaxf(a0.x, 0.f)) | ((unsigned)f2b(fmaxf(a0.y, 0.f)) << 16));
    v.y = (int)((unsigned)f2b(fmaxf(a0.z, 0.f)) | ((unsigned)f2b(fmaxf(a0.w, 0.f)) << 16));
    v.z = (int)((unsigned)f2b(fmaxf(a1.x, 0.f)) | ((unsigned)f2b(fmaxf(a1.y, 0.f)) << 16));
    v.w = (int)((unsigned)f2b(fmaxf(a1.z, 0.f)) | ((unsigned)f2b(fmaxf(a1.w, 0.f)) << 16));
    return v;
}

// ---------- stage 0 (one dispatch): blocks 0..1023 wmix both layers;
//            blocks 1024..2047 gather + zero denoms + partial histograms (R13-proven) ----------
__global__ __launch_bounds__(256) void prepmix_kernel(const float4* __restrict__ emb,
                                                      const int* __restrict__ entity,
                                                      const int* __restrict__ etype,
                                                      ushort4* __restrict__ xb4,
                                                      float4* __restrict__ zreg, int zcount4,
                                                      int* __restrict__ partial,
                                                      const float* __restrict__ att1,
                                                      const float* __restrict__ basis1,
                                                      unsigned short* __restrict__ W1,
                                                      const float* __restrict__ att2,
                                                      const float* __restrict__ basis2,
                                                      unsigned short* __restrict__ W2) {
    __shared__ __align__(16) unsigned short bt[64 * WSTRIDE];
    int t = threadIdx.x;
    if (blockIdx.x < 1024) {
        int wi = blockIdx.x;
        const float* att   = (wi >= 512) ? att2 : att1;
        const float* basis = (wi >= 512) ? basis2 : basis1;
        unsigned short* W  = (wi >= 512) ? W2 : W1;
        int io0 = (wi & 63) * 256;
        int r0 = ((wi >> 6) & 7) * 64;
#pragma unroll
        for (int p = 0; p < 16; p++) {
            int c = t + 256 * p;
            int k = c >> 6, of = c & 63;
            float4 v = *(const float4*)(basis + (size_t)k * (DIM * DIM) + io0 + of * 4);
            ushort4 s;
            s.x = f2b(v.x); s.y = f2b(v.y); s.z = f2b(v.z); s.w = f2b(v.w);
            *(ushort4*)&bt[k * WSTRIDE + of * 4] = s;
        }
        __syncthreads();

        int w = t >> 6, l = t & 63, n = l & 15, q = l >> 4;
        f32x4 acc[4][4] = {};                   // [rt][c]
#pragma unroll
        for (int kb = 0; kb < 2; kb++) {
            int kbase = kb * 32 + q * 8;
            bf16x8 a[4];
#pragma unroll
            for (int rt = 0; rt < 4; rt++) {
                int rm = min(r0 + rt * 16 + n, N_REL - 1);
                const float* ap = att + (size_t)rm * N_BASIS + kbase;
#pragma unroll
                for (int j = 0; j < 8; j++) a[rt][j] = u2b(f2b(ap[j]));
            }
#pragma unroll
            for (int c = 0; c < 4; c++) {
                int ob = w * 64 + c * 16 + n;
                bf16x8 b;
#pragma unroll
                for (int j = 0; j < 8; j++) b[j] = u2b(bt[(kbase + j) * WSTRIDE + ob]);
#pragma unroll
                for (int rt = 0; rt < 4; rt++)
                    acc[rt][c] = __builtin_amdgcn_mfma_f32_16x16x32_bf16(a[rt], b, acc[rt][c], 0, 0, 0);
            }
        }
#pragma unroll
        for (int rt = 0; rt < 4; rt++) {
#pragma unroll
            for (int c = 0; c < 4; c++) {
                int col = io0 + w * 64 + c * 16 + n;
#pragma unroll
                for (int rg = 0; rg < 4; rg++) {
                    int r = r0 + rt * 16 + q * 4 + rg;
                    if (r < N_REL) W[(size_t)r * (DIM * DIM) + col] = f2b(acc[rt][c][rg]);
                }
            }
        }
    } else {
        int pb = blockIdx.x - 1024;
        int gtid = pb * 256 + t;
        int gsz = 1024 * 256;
        int total4 = N_NODES * DIM / 4;
        for (int i = gtid; i < total4; i += gsz) {
            int n = i >> 5, rem = i & 31;
            float4 v = emb[(size_t)entity[n] * 32 + rem];
            ushort4 s;
            s.x = f2b(v.x); s.y = f2b(v.y); s.z = f2b(v.z); s.w = f2b(v.w);
            xb4[i] = s;
        }
        float4 z = make_float4(0.f, 0.f, 0.f, 0.f);
        for (int i = gtid; i < zcount4; i += gsz) zreg[i] = z;
        if (pb < HIST_BLKS) {
            int* ih = (int*)bt;
            for (int i = t; i < N_REL; i += 256) ih[i] = 0;
            __syncthreads();
            int e0 = pb * EDGES_PER_HIST;
            for (int e = e0 + t; e < e0 + EDGES_PER_HIST; e += 256)
                atomicAdd(&ih[etype[e]], 1);
            __syncthreads();
            for (int i = t; i < N_REL; i += 256) partial[pb * N_REL + i] = ih[i];
        }
    }
}

// ---------- scanr: sum partials + scan + chunk emit + cursor init (R13-proven) ----------
__global__ void scanr_kernel(const int* __restrict__ partial, int* __restrict__ offs,
                             int* __restrict__ cursor, int* __restrict__ chunk_r,
                             int* __restrict__ chunk_o, int* __restrict__ nchunks) {
    __shared__ int s[512];
    __shared__ int lnc;
    int t = threadIdx.x;
    int v = 0;
    if (t < N_REL) {
#pragma unroll
        for (int k = 0; k < HIST_BLKS; k++) v += partial[k * N_REL + t];
    }
    s[t] = v;
    if (t == 0) lnc = 0;
    __syncthreads();
    for (int d = 1; d < 512; d <<= 1) {
        int add = (t >= d) ? s[t - d] : 0;
        __syncthreads();
        s[t] += add;
        __syncthreads();
    }
    int excl = s[t] - v;
    if (t < N_REL) { offs[t] = excl; cursor[t] = excl; }
    if (t == 0) offs[N_REL] = N_EDGES;
    if (t < N_REL && v > 0) {
        int nc = (v + TILE_E - 1) / TILE_E;
        int cb = atomicAdd(&lnc, nc);
        for (int c = 0; c < nc; c++) { chunk_r[cb + c] = t; chunk_o[cb + c] = excl + c * TILE_E; }
    }
    __syncthreads();
    if (t == 0) *nchunks = lnc;
}

// ---------- fused: blocks [0,LOGIT_BLKS) logit(+optional scatter)+exp+denom;
//            blocks [LOGIT_BLKS,+ROOT_BLKS) rootgemm: target = x@rootM + bias.
//            x source: xb (bf16) if xf==nullptr, else relu(xf) fp32 inline ----------
__global__ __launch_bounds__(256) void fused_kernel(const unsigned short* __restrict__ xb,
                                                    const float* __restrict__ xf,
                                                    const float* __restrict__ w,
                                                    const int* __restrict__ src,
                                                    const int* __restrict__ dst,
                                                    const int* __restrict__ et,
                                                    int* __restrict__ cursor,
                                                    int* __restrict__ eids,
                                                    int do_scatter,
                                                    float* __restrict__ alpha,
                                                    float* __restrict__ den,
                                                    const float* __restrict__ rootM,
                                                    const float* __restrict__ bias,
                                                    float* __restrict__ target) {
    __shared__ __align__(16) unsigned short xrf[8192];   // 16 KB: A-frags for rootgemm blocks
    int t = threadIdx.x;
    if (blockIdx.x < LOGIT_BLKS) {
        // ---- logit + exp + denom (+ scatter) ----
        int wid = (blockIdx.x * 256 + t) >> 6;
        int lane = t & 63;
        int s = src[wid], d = dst[wid], r = et[wid];
        if (do_scatter && lane == 0) {
            int p = atomicAdd(&cursor[r], 1);
            eids[p] = wid;
        }
        float2 wv = ((const float2*)(w + (size_t)r * DIM))[lane];
        float v;
        if (xf == nullptr) {
            unsigned ax = ((const unsigned*)(xb + (size_t)s * DIM))[lane];
            unsigned bx = ((const unsigned*)(xb + (size_t)d * DIM))[lane];
            v = b2f((unsigned short)(ax & 0xFFFF)) * wv.x * b2f((unsigned short)(bx & 0xFFFF))
              + b2f((unsigned short)(ax >> 16)) * wv.y * b2f((unsigned short)(bx >> 16));
        } else {
            float2 axf = ((const float2*)(xf + (size_t)s * DIM))[lane];
            float2 bxf = ((const float2*)(xf + (size_t)d * DIM))[lane];
            v = fmaxf(axf.x, 0.f) * wv.x * fmaxf(bxf.x, 0.f)
              + fmaxf(axf.y, 0.f) * wv.y * fmaxf(bxf.y, 0.f);
        }
        for (int off = 32; off > 0; off >>= 1) v += __shfl_xor(v, off, 64);
        if (lane == 0) {
            float a = expf(v);
            alpha[wid] = a;
            atomicAdd(&den[d], a);
        }
    } else {
        // ---- rootgemm: target[row][col] = (x @ rootM)[row][col] + bias[col] ----
        int n0 = (blockIdx.x - LOGIT_BLKS) * 64;
#pragma unroll
        for (int p = 0; p < 4; p++) {
            int c = t + 256 * p;
            int g = c >> 6;
            int rt = g >> 2, kb = g & 3;
            int q = (c >> 4) & 3, m = c & 15;
            int row = n0 + rt * 16 + m;
            int oct = kb * 4 + q;
            int4 v = make_int4(0, 0, 0, 0);
            if (row < N_NODES) {
                if (xf == nullptr) {
                    v = *(const int4*)(xb + (size_t)row * DIM + oct * 8);
                } else {
                    const float4* sp = (const float4*)(xf + (size_t)row * DIM + oct * 8);
                    v = packrelu8(sp[0], sp[1]);
                }
            }
            *(int4*)&xrf[c * 8] = v;
        }
        __syncthreads();

        int w_ = t >> 6, l = t & 63, n = l & 15, q = l >> 4;
        f32x4 acc[2][4] = {};
#pragma unroll
        for (int kb = 0; kb < 4; kb++) {
            bf16x8 a[4];
#pragma unroll
            for (int rt = 0; rt < 4; rt++) a[rt] = *(const bf16x8*)&xrf[((rt * 4 + kb) * 64 + l) * 8];
            int kbase = kb * 32 + q * 8;
#pragma unroll
            for (int c = 0; c < 2; c++) {
                int col = (w_ * 2 + c) * 16 + n;
                bf16x8 b;
#pragma unroll
                for (int j = 0; j < 8; j++) b[j] = u2b(f2b(rootM[(kbase + j) * DIM + col]));
#pragma unroll
                for (int rt = 0; rt < 4; rt++)
                    acc[c][rt] = __builtin_amdgcn_mfma_f32_16x16x32_bf16(a[rt], b, acc[c][rt], 0, 0, 0);
            }
        }
#pragma unroll
        for (int c = 0; c < 2; c++) {
            int col = (w_ * 2 + c) * 16 + n;
            float bo = bias[col];
#pragma unroll
            for (int rt = 0; rt < 4; rt++) {
#pragma unroll
                for (int rg = 0; rg < 4; rg++) {
                    int row = n0 + rt * 16 + q * 4 + rg;
                    if (row < N_NODES)
                        target[(size_t)row * DIM + col] = acc[c][rt][rg] + bo;
                }
            }
        }
    }
}

// ---------- msg: per 64-edge chunk, (64x128)@(128x128) MFMA + alpha-scaled atomicAdd.
//            x source: xb (bf16) if xf==nullptr, else relu(xf) fp32 inline ----------
__global__ __launch_bounds__(256) void msg_kernel(const unsigned short* __restrict__ xb,
                                                  const float* __restrict__ xf,
                                                  const unsigned short* __restrict__ W,
                                                  const int* __restrict__ chunk_r,
                                                  const int* __restrict__ chunk_off,
                                                  const int* __restrict__ nchunks,
                                                  const int* __restrict__ eids,
                                                  const int* __restrict__ offs,
                                                  const int* __restrict__ src,
                                                  const int* __restrict__ dst,
                                                  const float* __restrict__ ae,
                                                  const float* __restrict__ denom,
                                                  float* __restrict__ outacc) {
    if ((int)blockIdx.x >= *nchunks) return;
    int r = chunk_r[blockIdx.x];
    int base = chunk_off[blockIdx.x];
    int nE = min(TILE_E, offs[r + 1] - base);
    const unsigned short* Wr = W + (size_t)r * (DIM * DIM);

    __shared__ unsigned short wt[128 * 136];   // [k][o] pad
    __shared__ unsigned short xjf[8192];       // A-frag order, 64 edges
    __shared__ float scf[TILE_E];
    __shared__ int sdd[TILE_E];

    int t = threadIdx.x;
    if (t < TILE_E) {
        if (t < nE) {
            int e = eids[base + t];
            int d_ = dst[e];
            sdd[t] = d_;
            scf[t] = ae[e] / denom[d_];
        } else { sdd[t] = 0; scf[t] = 0.f; }
    }
#pragma unroll
    for (int p = 0; p < 4; p++) {
        int c = t + 256 * p;
        int g = c >> 6;
        int rt = g >> 2, kb = g & 3;
        int q = (c >> 4) & 3, m = c & 15;
        int e = rt * 16 + m;
        int oct = kb * 4 + q;
        int4 v = make_int4(0, 0, 0, 0);
        if (e < nE) {
            size_t rowoff = (size_t)src[eids[base + e]] * DIM + oct * 8;
            if (xf == nullptr) {
                v = *(const int4*)(xb + rowoff);
            } else {
                const float4* sp = (const float4*)(xf + rowoff);
                v = packrelu8(sp[0], sp[1]);
            }
        }
        *(int4*)&xjf[c * 8] = v;
    }
#pragma unroll
    for (int p = 0; p < 8; p++) {
        int c = t + 256 * p;
        int k = c >> 4, oct = c & 15;
        int4 v = *(const int4*)(Wr + k * DIM + oct * 8);
        *(int4*)&wt[k * 136 + oct * 8] = v;
    }
    __syncthreads();

    int w = t >> 6, l = t & 63, n = l & 15, q = l >> 4;
    f32x4 acc[2][4] = {};                       // [ct-local][rt]
#pragma unroll
    for (int kb = 0; kb < 4; kb++) {
        bf16x8 a[4];
#pragma unroll
        for (int rt = 0; rt < 4; rt++) a[rt] = *(const bf16x8*)&xjf[((rt * 4 + kb) * 64 + l) * 8];
        int kbase = kb * 32 + q * 8;
#pragma unroll
        for (int c = 0; c < 2; c++) {
            int ob = (w * 2 + c) * 16 + n;
            bf16x8 b;
#pragma unroll
            for (int j = 0; j < 8; j++) b[j] = u2b(wt[(kbase + j) * 136 + ob]);
#pragma unroll
            for (int rt = 0; rt < 4; rt++)
                acc[c][rt] = __builtin_amdgcn_mfma_f32_16x16x32_bf16(a[rt], b, acc[c][rt], 0, 0, 0);
        }
    }
#pragma unroll
    for (int c = 0; c < 2; c++) {
        int col = (w * 2 + c) * 16 + n;
#pragma unroll
        for (int rt = 0; rt < 4; rt++) {
#pragma unroll
            for (int rg = 0; rg < 4; rg++) {
                int e = rt * 16 + q * 4 + rg;
                if (e < nE)
                    atomicAdd(&outacc[(size_t)sdd[e] * DIM + col], scf[e] * acc[c][rt][rg]);
            }
        }
    }
}

extern "C" void kernel_launch(void* const* d_in, const int* in_sizes, int n_in,
                              void* d_out, int out_size, void* d_ws, size_t ws_size,
                              hipStream_t stream) {
    const int N = N_NODES, E = N_EDGES, R = N_REL;

    const int* entity = (const int*)d_in[0];
    const int* eidx   = (const int*)d_in[1];
    const int* src    = eidx;
    const int* dst    = eidx + E;
    const int* etype  = (const int*)d_in[2];
    const float* emb  = (const float*)d_in[3];
    const float* basis1 = (const float*)d_in[4];
    const float* att1   = (const float*)d_in[5];
    const float* w1     = (const float*)d_in[6];
    const float* root1  = (const float*)d_in[7];
    const float* bias1  = (const float*)d_in[8];
    const float* basis2 = (const float*)d_in[9];
    const float* att2   = (const float*)d_in[10];
    const float* w2     = (const float*)d_in[11];
    const float* root2  = (const float*)d_in[12];
    const float* bias2  = (const float*)d_in[13];
    float* out = (float*)d_out;

    size_t off = 0;
    auto alloc = [&](size_t bytes) -> void* {
        void* p = (char*)d_ws + off;
        off += (bytes + 255) & ~(size_t)255;
        return p;
    };
    unsigned short* W1 = (unsigned short*)alloc((size_t)R * DIM * DIM * 2);
    unsigned short* W2 = (unsigned short*)alloc((size_t)R * DIM * DIM * 2);
    unsigned short* xb = (unsigned short*)alloc((size_t)N * DIM * 2);
    float* acc1   = (float*)alloc((size_t)N * DIM * 4);
    // zero region: denom1 | denom2 only
    float* zreg   = (float*)alloc((size_t)2 * N * 4);
    float* denom1 = zreg;
    float* denom2 = zreg + N;
    float* alpha  = (float*)alloc((size_t)E * 4);
    int* partial  = (int*)alloc((size_t)HIST_BLKS * R * 4);
    int* nchunks  = (int*)alloc(256);
    int* offs     = (int*)alloc((size_t)(R + 1) * 4);
    int* cursor   = (int*)alloc((size_t)R * 4);
    int* eids     = (int*)alloc((size_t)E * 4);
    int* chunk_r  = (int*)alloc((size_t)MAXCH * 4);
    int* chunk_o  = (int*)alloc((size_t)MAXCH * 4);

    int zcount4 = 2 * N / 4;

    // ---- stage 0: wmix(both) + gather + zero denoms + partial hist ----
    prepmix_kernel<<<2048, 256, 0, stream>>>((const float4*)emb, entity, etype,
                                             (ushort4*)xb, (float4*)zreg, zcount4, partial,
                                             att1, basis1, W1, att2, basis2, W2);
    // ---- stage 1: plan ----
    scanr_kernel<<<1, 512, 0, stream>>>(partial, offs, cursor, chunk_r, chunk_o, nchunks);

    // ---- layer 1: xb -> acc1 (rootgemm writes, msg adds) ----
    fused_kernel<<<LOGIT_BLKS + ROOT_BLKS, 256, 0, stream>>>(
        xb, nullptr, w1, src, dst, etype, cursor, eids, 1, alpha, denom1, root1, bias1, acc1);
    msg_kernel<<<MAXCH, 256, 0, stream>>>(xb, nullptr, W1, chunk_r, chunk_o, nchunks,
                                          eids, offs, src, dst, alpha, denom1, acc1);

    // ---- layer 2: relu(acc1) read inline -> out ----
    fused_kernel<<<LOGIT_BLKS + ROOT_BLKS, 256, 0, stream>>>(
        nullptr, acc1, w2, src, dst, etype, cursor, eids, 0, alpha, denom2, root2, bias2, out);
    msg_kernel<<<MAXCH, 256, 0, stream>>>(nullptr, acc1, W2, chunk_r, chunk_o, nchunks,
                                          eids, offs, src, dst, alpha, denom2, out);
}